// Round 2
// baseline (294.712 us; speedup 1.0000x reference)
//
#include <hip/hip_runtime.h>
#include <math.h>

// Problem constants (HeadAttention_738734374917)
#define Bn  8
#define Nn  2048
#define Dn  1024
#define DHn 64
#define PAD  72  // LDS row pitch (shorts) for 64-wide tiles
#define PADP 72  // LDS row pitch for Pt — 72 keeps b64 writes / b128 reads at bank-floor

typedef __attribute__((ext_vector_type(8))) short bf16x8;  // 8 bf16 = 4 VGPRs
typedef __attribute__((ext_vector_type(4))) float f32x4;

static __device__ inline short f2bf(float f) {
    unsigned u = __builtin_bit_cast(unsigned, f);
    u += 0x7FFFu + ((u >> 16) & 1u);     // round-to-nearest-even
    return (short)(u >> 16);
}
static __device__ inline bf16x8 pack8(float4 a, float4 b) {
    bf16x8 v;
    v[0] = f2bf(a.x); v[1] = f2bf(a.y); v[2] = f2bf(a.z); v[3] = f2bf(a.w);
    v[4] = f2bf(b.x); v[5] = f2bf(b.y); v[6] = f2bf(b.z); v[7] = f2bf(b.w);
    return v;
}

// ---------------------------------------------------------------------------
// Wt in B-FRAG-MAJOR order: Wtf[ntg 0..11][kt 0..15][half 0..1][lane 0..63][e 0..7]
// Coalesced 32B loads -> LDS transpose -> b128 frag store.
// Also zeroes the 384 last-arriver counters (cnt[0..255]=colsum, [256..383]=attnout).
// ---------------------------------------------------------------------------
__global__ __launch_bounds__(128) void wt_kernel(
    const float* __restrict__ Wq, const float* __restrict__ Wk,
    const float* __restrict__ Wv, short* __restrict__ Wtf, int* __restrict__ cnt)
{
    __shared__ float wsm[64][20];   // [k][n], pad 20 keeps float4 stores 16B-aligned
    const int nt = blockIdx.x / 16, kt = blockIdx.x % 16;
    const int t = threadIdx.x;
    const int gid = blockIdx.x * 128 + t;
    if (gid < 384) cnt[gid] = 0;

    const int mat = nt >> 2;
    const float* Wm = (mat == 0) ? Wq : (mat == 1 ? Wk : Wv);
    {
        const int k = t >> 1, n8 = (t & 1) * 8;
        const float* src = &Wm[(size_t)(kt * 64 + k) * DHn + (nt & 3) * 16 + n8];
        const float4 f0 = ((const float4*)src)[0];
        const float4 f1 = ((const float4*)src)[1];
        *(float4*)&wsm[k][n8]     = f0;
        *(float4*)&wsm[k][n8 + 4] = f1;
    }
    __syncthreads();
    const int half = t >> 6, l = t & 63;
    const int c = l & 15, quad = l >> 4;
    bf16x8 o;
#pragma unroll
    for (int e = 0; e < 8; ++e) o[e] = f2bf(wsm[half * 32 + quad * 8 + e][c]);
    *(bf16x8*)&Wtf[((((size_t)nt * 16 + kt) * 2 + half) * 64 + l) * 8] = o;
}

// ---------------------------------------------------------------------------
// K1: QKV projection: M=32, grid 512, dbuf xs, one barrier/kt, frag-major Wtf.
// 4-deep register-ring x prefetch (static indices via full unroll) so HBM
// latency (~900cy) is covered by ~3.5 iterations of slack.
// Outputs: Qb[i][d], Kb[j][d]*0.125 (bf16), Vtf32[b][d][j] (f32, pre-scale).
// ---------------------------------------------------------------------------
__global__ __launch_bounds__(256) void qkv_kernel(
    const float* __restrict__ x, const short* __restrict__ Wtf,
    const float* __restrict__ bq, const float* __restrict__ bk,
    const float* __restrict__ bv,
    short* __restrict__ Qb, short* __restrict__ Kb, float* __restrict__ Vtf32)
{
    __shared__ __attribute__((aligned(16))) short xs[2][32][PAD];

    const int t = threadIdx.x;
    const int w = t >> 6, l = t & 63;
    const int c = l & 15, quad = l >> 4;
    const int ibase = blockIdx.x * 32;
    const int r0 = t >> 3, kc = t & 7;

    const float* xrow = &x[(size_t)(ibase + r0) * Dn + kc * 8];

    {
        const float4 a = ((const float4*)xrow)[0];
        const float4 b = ((const float4*)xrow)[1];
        *(bf16x8*)&xs[0][r0][kc * 8] = pack8(a, b);
    }

    // register ring: slot (k & 3) holds x data for iteration k
    float4 ra[4], rb[4];
#pragma unroll
    for (int k = 1; k <= 3; ++k) {
        ra[k] = ((const float4*)(xrow + k * 64))[0];
        rb[k] = ((const float4*)(xrow + k * 64))[1];
    }

    f32x4 acc[2][3];
#pragma unroll
    for (int mt = 0; mt < 2; ++mt)
#pragma unroll
        for (int nt = 0; nt < 3; ++nt) acc[mt][nt] = (f32x4){0.f, 0.f, 0.f, 0.f};

    __syncthreads();

#pragma unroll
    for (int kt = 0; kt < 16; ++kt) {
        const int cur = kt & 1;
        if (kt + 4 <= 15) {
            ra[kt & 3] = ((const float4*)(xrow + (kt + 4) * 64))[0];
            rb[kt & 3] = ((const float4*)(xrow + (kt + 4) * 64))[1];
        }
#pragma unroll
        for (int h = 0; h < 2; ++h) {
            const bf16x8 af0 = *(const bf16x8*)&xs[cur][c][h * 32 + quad * 8];
            const bf16x8 af1 = *(const bf16x8*)&xs[cur][16 + c][h * 32 + quad * 8];
#pragma unroll
            for (int nt = 0; nt < 3; ++nt) {
                const int ntg = w * 3 + nt;
                const bf16x8 bf = *(const bf16x8*)&Wtf[((((size_t)ntg * 16 + kt) * 2 + h) * 64 + l) * 8];
                acc[0][nt] = __builtin_amdgcn_mfma_f32_16x16x32_bf16(af0, bf, acc[0][nt], 0, 0, 0);
                acc[1][nt] = __builtin_amdgcn_mfma_f32_16x16x32_bf16(af1, bf, acc[1][nt], 0, 0, 0);
            }
        }
        if (kt < 15)
            *(bf16x8*)&xs[1 - cur][r0][kc * 8] = pack8(ra[(kt + 1) & 3], rb[(kt + 1) & 3]);
        __syncthreads();
    }

#pragma unroll
    for (int nt = 0; nt < 3; ++nt) {
        const int col = w * 48 + nt * 16 + c;
        const int mat = col >> 6, cm = col & 63;
        const float bias = (mat == 0 ? bq : (mat == 1 ? bk : bv))[cm];
#pragma unroll
        for (int mt = 0; mt < 2; ++mt) {
            if (mat == 2) {
                const int row = ibase + mt * 16 + quad * 4;
                const int b = row >> 11, i = row & (Nn - 1);
                float4 o;
                o.x = acc[mt][nt][0] + bias;
                o.y = acc[mt][nt][1] + bias;
                o.z = acc[mt][nt][2] + bias;
                o.w = acc[mt][nt][3] + bias;
                *(float4*)&Vtf32[((size_t)b * DHn + cm) * Nn + i] = o;
            } else {
                const float s = (mat == 1) ? 0.125f : 1.0f;
                short* Out = (mat == 0) ? Qb : Kb;
#pragma unroll
                for (int r = 0; r < 4; ++r)
                    Out[(size_t)(ibase + mt * 16 + quad * 4 + r) * DHn + cm] =
                        f2bf((acc[mt][nt][r] + bias) * s);
            }
        }
    }
}

// ---------------------------------------------------------------------------
// K2: l_part[s][b][j] = sum_{i in split s} exp(Q_i . K'_j).
// b = bid&7 so each XCD's L2 holds only its batch's Q/K.
// FUSED vscale: the last-arriving of the 4 split-blocks per (b,jt) rescales
// V for its 64 j-columns: Vt = bf16(Vtf32 / l_j). Counter zeroed by wt_kernel.
// ---------------------------------------------------------------------------
__global__ __launch_bounds__(256) void colsum_kernel(
    const short* __restrict__ Qb, const short* __restrict__ Kb,
    const float* __restrict__ Vtf32, float* __restrict__ lpart,
    short* __restrict__ Vt, int* __restrict__ cnt)
{
    __shared__ __attribute__((aligned(16))) short Qw[4][2][32][PAD];
    __shared__ float red[16][64];   // red[0][0] doubles as the last-arriver flag

    const int t = threadIdx.x;
    const int w = t >> 6, l = t & 63;
    const int c = l & 15, quad = l >> 4;
    const int bid = blockIdx.x;
    const int b = bid & 7, jt = (bid >> 3) & 31, s = (bid >> 8) & 3;
    const int jbase = jt * 64;
    const int srow = l >> 1, scoff = (l & 1) * 32;   // staging: 32 rows, half-row/lane

    bf16x8 kb[4][2];
#pragma unroll
    for (int nt = 0; nt < 4; ++nt)
#pragma unroll
        for (int kk = 0; kk < 2; ++kk)
            kb[nt][kk] = *(const bf16x8*)&Kb[((size_t)b * Nn + jbase + nt * 16 + c) * DHn
                                             + kk * 32 + quad * 8];

    // wave w owns contiguous 128 i: s*512 + w*128, 4 iters of 32 rows
    const short* qbase = &Qb[((size_t)b * Nn + s * 512 + w * 128 + srow) * DHn + scoff];

    // stage it2=0 into buf 0 (wave-private, 4 b128/lane)
#pragma unroll
    for (int k = 0; k < 4; ++k)
        *(bf16x8*)&Qw[w][0][srow][scoff + k * 8] = *(const bf16x8*)(qbase + k * 8);

    float lsum[4] = {0.f, 0.f, 0.f, 0.f};

    for (int it2 = 0; it2 < 4; ++it2) {
        const int cur = it2 & 1;
        bf16x8 p[4];
        if (it2 < 3) {
            const short* pq = qbase + (size_t)(it2 + 1) * 32 * DHn;
#pragma unroll
            for (int k = 0; k < 4; ++k) p[k] = *(const bf16x8*)(pq + k * 8);
        }
        // two independent 16-row chunks
#pragma unroll
        for (int cc2 = 0; cc2 < 2; ++cc2) {
            const bf16x8 aq0 = *(const bf16x8*)&Qw[w][cur][cc2 * 16 + c][quad * 8];
            const bf16x8 aq1 = *(const bf16x8*)&Qw[w][cur][cc2 * 16 + c][32 + quad * 8];
#pragma unroll
            for (int nt = 0; nt < 4; ++nt) {
                f32x4 sv = (f32x4){0.f, 0.f, 0.f, 0.f};
                sv = __builtin_amdgcn_mfma_f32_16x16x32_bf16(aq0, kb[nt][0], sv, 0, 0, 0);
                sv = __builtin_amdgcn_mfma_f32_16x16x32_bf16(aq1, kb[nt][1], sv, 0, 0, 0);
                lsum[nt] += __expf(sv[0]) + __expf(sv[1]) + __expf(sv[2]) + __expf(sv[3]);
            }
        }
        if (it2 < 3) {
#pragma unroll
            for (int k = 0; k < 4; ++k)
                *(bf16x8*)&Qw[w][1 - cur][srow][scoff + k * 8] = p[k];
        }
        // no barrier: Qw[w] is wave-private, DS ops in-order per wave
    }

#pragma unroll
    for (int nt = 0; nt < 4; ++nt) red[w * 4 + quad][nt * 16 + c] = lsum[nt];
    __syncthreads();
    if (t < 64) {
        float sum = 0.f;
#pragma unroll
        for (int r = 0; r < 16; ++r) sum += red[r][t];
        lpart[((size_t)s * Bn + b) * Nn + jbase + t] = sum;   // plain store
    }

    // ---- last-arriver vscale for this (b, jt) ----
    __threadfence();          // release our lpart stores (device scope)
    __syncthreads();          // drains vmcnt(0): block's stores complete
    if (t == 0) {
        const int old = atomicAdd(&cnt[b * 32 + jt], 1);
        red[0][0] = (old == 3) ? 1.0f : 0.0f;
    }
    __syncthreads();
    if (red[0][0] != 0.0f) {
        __threadfence();      // acquire side
        const int d = t >> 2, jc = (t & 3) * 16;
        const float* lp = &lpart[(size_t)b * Nn + jbase + jc];
        float lsum16[16];
#pragma unroll
        for (int jj = 0; jj < 16; ++jj)
            lsum16[jj] = lp[jj] + lp[(size_t)Bn * Nn + jj]
                       + lp[2 * (size_t)Bn * Nn + jj] + lp[3 * (size_t)Bn * Nn + jj];
        const size_t voff = ((size_t)b * DHn + d) * Nn + jbase + jc;
        const float4* vsrc = (const float4*)&Vtf32[voff];
        float4 a0 = vsrc[0], a1 = vsrc[1], a2 = vsrc[2], a3 = vsrc[3];
        a0.x /= lsum16[0];  a0.y /= lsum16[1];  a0.z /= lsum16[2];  a0.w /= lsum16[3];
        a1.x /= lsum16[4];  a1.y /= lsum16[5];  a1.z /= lsum16[6];  a1.w /= lsum16[7];
        a2.x /= lsum16[8];  a2.y /= lsum16[9];  a2.z /= lsum16[10]; a2.w /= lsum16[11];
        a3.x /= lsum16[12]; a3.y /= lsum16[13]; a3.z /= lsum16[14]; a3.w /= lsum16[15];
        *(bf16x8*)&Vt[voff]     = pack8(a0, a1);
        *(bf16x8*)&Vt[voff + 8] = pack8(a2, a3);
    }
}

// ---------------------------------------------------------------------------
// K3: outp[s][i,:] = sum_{j in s} exp(Q_i.K'_j) V'[j,:].
// Grid = (b 8, i-tile 16, j-split 4) = 512, b = bid&7 (XCD-local K/V/Q).
// SWAPPED QK^T: mfma(K,Q) -> S^T frag so the P transpose is b64 writes.
// FUSED outreduce: last-arriving of the 4 j-split blocks per (b,it) sums the
// 4 outp partials into out.
// ---------------------------------------------------------------------------
__global__ __launch_bounds__(256) void attnout_kernel(
    const short* __restrict__ Qb, const short* __restrict__ Kb,
    const short* __restrict__ Vt, float* __restrict__ outp,
    float* __restrict__ out, int* __restrict__ cnt)
{
    __shared__ __attribute__((aligned(16))) short Ks[2][64][PAD];
    __shared__ __attribute__((aligned(16))) short Vs[2][64][PAD];
    __shared__ __attribute__((aligned(16))) short Pt[4][2][16][PADP];  // [w][sub][i][j]
    __shared__ int lastf;

    const int t = threadIdx.x;
    const int w = t >> 6, lane = t & 63;
    const int c = lane & 15, quad = lane >> 4;
    const int bid = blockIdx.x;
    const int b = bid & 7, rem = bid >> 3, it = rem >> 2, s = rem & 3;
    const int ibase = it * 128;
    const int r0 = t >> 2, cc = (t & 3) * 16;

    // Q B-frags (swapped mfma uses Q as B operand): 2 subtiles x 2 halves
    bf16x8 aq[2][2];
#pragma unroll
    for (int sub = 0; sub < 2; ++sub) {
        const size_t qrow = (size_t)b * Nn + ibase + w * 32 + sub * 16 + c;
        aq[sub][0] = *(const bf16x8*)&Qb[qrow * DHn + quad * 8];
        aq[sub][1] = *(const bf16x8*)&Qb[qrow * DHn + 32 + quad * 8];
    }

    const short* kbase = &Kb[((size_t)b * Nn + s * 512 + r0) * DHn + cc];
    const short* vbase = &Vt[((size_t)b * DHn + r0) * Nn + s * 512 + cc];

    // stage tile 0
    *(bf16x8*)&Ks[0][r0][cc]     = *(const bf16x8*)kbase;
    *(bf16x8*)&Ks[0][r0][cc + 8] = *(const bf16x8*)(kbase + 8);
    *(bf16x8*)&Vs[0][r0][cc]     = *(const bf16x8*)vbase;
    *(bf16x8*)&Vs[0][r0][cc + 8] = *(const bf16x8*)(vbase + 8);

    f32x4 acc[2][4];
#pragma unroll
    for (int sub = 0; sub < 2; ++sub)
#pragma unroll
        for (int dn = 0; dn < 4; ++dn) acc[sub][dn] = (f32x4){0.f, 0.f, 0.f, 0.f};
    __syncthreads();

    for (int jt2 = 0; jt2 < 8; ++jt2) {
        const int cur = jt2 & 1;
        bf16x8 pk0, pk1, pv0, pv1;
        if (jt2 < 7) {
            const short* pk = kbase + (size_t)(jt2 + 1) * 64 * DHn;
            pk0 = *(const bf16x8*)pk; pk1 = *(const bf16x8*)(pk + 8);
            const short* pv = vbase + (jt2 + 1) * 64;
            pv0 = *(const bf16x8*)pv; pv1 = *(const bf16x8*)(pv + 8);
        }

        // S^T for both subtiles, sharing K A-frag reads; write Pt as b64
#pragma unroll
        for (int nt = 0; nt < 4; ++nt) {
            const bf16x8 kb0 = *(const bf16x8*)&Ks[cur][nt * 16 + c][quad * 8];
            const bf16x8 kb1 = *(const bf16x8*)&Ks[cur][nt * 16 + c][32 + quad * 8];
#pragma unroll
            for (int sub = 0; sub < 2; ++sub) {
                f32x4 sv = (f32x4){0.f, 0.f, 0.f, 0.f};
                sv = __builtin_amdgcn_mfma_f32_16x16x32_bf16(kb0, aq[sub][0], sv, 0, 0, 0);
                sv = __builtin_amdgcn_mfma_f32_16x16x32_bf16(kb1, aq[sub][1], sv, 0, 0, 0);
                ushort4 o;
                o.x = (unsigned short)f2bf(__expf(sv[0]));
                o.y = (unsigned short)f2bf(__expf(sv[1]));
                o.z = (unsigned short)f2bf(__expf(sv[2]));
                o.w = (unsigned short)f2bf(__expf(sv[3]));
                // lane holds i=c, j = nt*16 + quad*4 + r  (j-contiguous!)
                *(ushort4*)&Pt[w][sub][c][nt * 16 + quad * 4] = o;
            }
        }
        // A-frags from Pt (wave-private, same-wave DS in-order)
        bf16x8 ap[2][2];
#pragma unroll
        for (int sub = 0; sub < 2; ++sub) {
            ap[sub][0] = *(const bf16x8*)&Pt[w][sub][c][quad * 8];
            ap[sub][1] = *(const bf16x8*)&Pt[w][sub][c][32 + quad * 8];
        }
#pragma unroll
        for (int dn = 0; dn < 4; ++dn) {
            const bf16x8 vb0 = *(const bf16x8*)&Vs[cur][dn * 16 + c][quad * 8];
            const bf16x8 vb1 = *(const bf16x8*)&Vs[cur][dn * 16 + c][32 + quad * 8];
#pragma unroll
            for (int sub = 0; sub < 2; ++sub) {
                acc[sub][dn] = __builtin_amdgcn_mfma_f32_16x16x32_bf16(ap[sub][0], vb0, acc[sub][dn], 0, 0, 0);
                acc[sub][dn] = __builtin_amdgcn_mfma_f32_16x16x32_bf16(ap[sub][1], vb1, acc[sub][dn], 0, 0, 0);
            }
        }

        if (jt2 < 7) {
            *(bf16x8*)&Ks[1 - cur][r0][cc]     = pk0;
            *(bf16x8*)&Ks[1 - cur][r0][cc + 8] = pk1;
            *(bf16x8*)&Vs[1 - cur][r0][cc]     = pv0;
            *(bf16x8*)&Vs[1 - cur][r0][cc + 8] = pv1;
        }
        __syncthreads();
    }

    float* op = outp + (size_t)s * (Bn * Nn * DHn) + ((size_t)b * Nn + ibase) * DHn;
#pragma unroll
    for (int sub = 0; sub < 2; ++sub)
#pragma unroll
        for (int dn = 0; dn < 4; ++dn)
#pragma unroll
            for (int r = 0; r < 4; ++r)
                op[(w * 32 + sub * 16 + quad * 4 + r) * DHn + dn * 16 + c] = acc[sub][dn][r];

    // ---- last-arriver reduce for this (b, it) ----
    __threadfence();          // release our outp stores
    __syncthreads();          // drains vmcnt(0): block's stores complete
    if (t == 0) lastf = (atomicAdd(&cnt[b * 16 + it], 1) == 3);
    __syncthreads();
    if (lastf) {
        __threadfence();      // acquire side
        const size_t base = (((size_t)b * Nn + ibase) * DHn) >> 2;   // float4 index
        const float4* P = (const float4*)outp;
        float4* O = (float4*)out;
        const size_t sstride = ((size_t)Bn * Nn * DHn) >> 2;
#pragma unroll
        for (int k = 0; k < 8; ++k) {
            const size_t idx = base + k * 256 + t;
            float4 r = P[idx];
#pragma unroll
            for (int s2 = 1; s2 < 4; ++s2) {
                const float4 a2 = P[idx + (size_t)s2 * sstride];
                r.x += a2.x; r.y += a2.y; r.z += a2.z; r.w += a2.w;
            }
            O[idx] = r;
        }
    }
}

// ---------------------------------------------------------------------------
extern "C" void kernel_launch(void* const* d_in, const int* in_sizes, int n_in,
                              void* d_out, int out_size, void* d_ws, size_t ws_size,
                              hipStream_t stream)
{
    const float* x  = (const float*)d_in[0];
    const float* Wq = (const float*)d_in[1];
    const float* bq = (const float*)d_in[2];
    const float* Wk = (const float*)d_in[3];
    const float* bk = (const float*)d_in[4];
    const float* Wv = (const float*)d_in[5];
    const float* bv = (const float*)d_in[6];
    float* out = (float*)d_out;

    char* ws = (char*)d_ws;
    short* Qb    = (short*)(ws);                                   // 2 MB
    short* Kb    = (short*)(ws + (size_t)(1 << 21));               // 2 MB
    short* Vt    = (short*)(ws + (size_t)(2 << 21));               // 2 MB [b][d][j] bf16 (scaled)
    short* Wtf   = (short*)(ws + (size_t)(3 << 21));               // 384 KB (frag-major)
    float* lpart = (float*)(ws + (size_t)(3 << 21) + (1 << 19));   // 256 KB (4 splits)
    int*   cnt   = (int*)  (ws + (size_t)(3 << 21) + (1 << 19) + (1 << 18)); // 1.5 KB counters
    float* Vtf32 = (float*)(ws + (size_t)(7 << 20));               // 4 MB [b][d][j] f32
    float* outp  = (float*)(ws + (size_t)(11 << 20));              // 16 MB (4 partials)

    wt_kernel<<<dim3(192), dim3(128), 0, stream>>>(Wq, Wk, Wv, Wtf, cnt);
    qkv_kernel<<<dim3(512), dim3(256), 0, stream>>>(x, Wtf, bq, bk, bv, Qb, Kb, Vtf32);
    colsum_kernel<<<dim3(1024), dim3(256), 0, stream>>>(Qb, Kb, Vtf32, lpart, Vt, cnt);
    attnout_kernel<<<dim3(512), dim3(256), 0, stream>>>(Qb, Kb, Vt, outp, out, cnt + 256);
}

// Round 3
// 197.658 us; speedup vs baseline: 1.4910x; 1.4910x over previous
//
#include <hip/hip_runtime.h>
#include <math.h>

// Problem constants (HeadAttention_738734374917)
#define Bn  8
#define Nn  2048
#define Dn  1024
#define DHn 64
#define PAD  72  // LDS row pitch (shorts) for 64-wide tiles
#define PADP 72  // LDS row pitch for Pt — 144B = 16B-aligned, b64 writes / b128 reads at bank-floor

typedef __attribute__((ext_vector_type(8))) short bf16x8;  // 8 bf16 = 4 VGPRs
typedef __attribute__((ext_vector_type(4))) float f32x4;

static __device__ inline short f2bf(float f) {
    unsigned u = __builtin_bit_cast(unsigned, f);
    u += 0x7FFFu + ((u >> 16) & 1u);     // round-to-nearest-even
    return (short)(u >> 16);
}
static __device__ inline bf16x8 pack8(float4 a, float4 b) {
    bf16x8 v;
    v[0] = f2bf(a.x); v[1] = f2bf(a.y); v[2] = f2bf(a.z); v[3] = f2bf(a.w);
    v[4] = f2bf(b.x); v[5] = f2bf(b.y); v[6] = f2bf(b.z); v[7] = f2bf(b.w);
    return v;
}

// ---------------------------------------------------------------------------
// Wt in B-FRAG-MAJOR order: Wtf[ntg 0..11][kt 0..15][half 0..1][lane 0..63][e 0..7]
// Coalesced 32B loads -> LDS transpose -> b128 frag store.
// ---------------------------------------------------------------------------
__global__ __launch_bounds__(128) void wt_kernel(
    const float* __restrict__ Wq, const float* __restrict__ Wk,
    const float* __restrict__ Wv, short* __restrict__ Wtf)
{
    __shared__ float wsm[64][20];   // [k][n], pad 20 keeps float4 stores 16B-aligned
    const int nt = blockIdx.x / 16, kt = blockIdx.x % 16;
    const int t = threadIdx.x;

    const int mat = nt >> 2;
    const float* Wm = (mat == 0) ? Wq : (mat == 1 ? Wk : Wv);
    {
        const int k = t >> 1, n8 = (t & 1) * 8;
        const float* src = &Wm[(size_t)(kt * 64 + k) * DHn + (nt & 3) * 16 + n8];
        const float4 f0 = ((const float4*)src)[0];
        const float4 f1 = ((const float4*)src)[1];
        *(float4*)&wsm[k][n8]     = f0;
        *(float4*)&wsm[k][n8 + 4] = f1;
    }
    __syncthreads();
    const int half = t >> 6, l = t & 63;
    const int c = l & 15, quad = l >> 4;
    bf16x8 o;
#pragma unroll
    for (int e = 0; e < 8; ++e) o[e] = f2bf(wsm[half * 32 + quad * 8 + e][c]);
    *(bf16x8*)&Wtf[((((size_t)nt * 16 + kt) * 2 + half) * 64 + l) * 8] = o;
}

// ---------------------------------------------------------------------------
// K1: QKV projection: M=32, grid 512, dbuf xs, one barrier/kt, frag-major Wtf.
// 4-deep register-ring x prefetch (static indices via full unroll).
// Outputs: Qb[i][d], Kb[j][d]*0.125 (bf16), Vtf32[b][d][j] (f32, pre-scale).
// ---------------------------------------------------------------------------
__global__ __launch_bounds__(256) void qkv_kernel(
    const float* __restrict__ x, const short* __restrict__ Wtf,
    const float* __restrict__ bq, const float* __restrict__ bk,
    const float* __restrict__ bv,
    short* __restrict__ Qb, short* __restrict__ Kb, float* __restrict__ Vtf32)
{
    __shared__ __attribute__((aligned(16))) short xs[2][32][PAD];

    const int t = threadIdx.x;
    const int w = t >> 6, l = t & 63;
    const int c = l & 15, quad = l >> 4;
    const int ibase = blockIdx.x * 32;
    const int r0 = t >> 3, kc = t & 7;

    const float* xrow = &x[(size_t)(ibase + r0) * Dn + kc * 8];

    {
        const float4 a = ((const float4*)xrow)[0];
        const float4 b = ((const float4*)xrow)[1];
        *(bf16x8*)&xs[0][r0][kc * 8] = pack8(a, b);
    }

    // register ring: slot (k & 3) holds x data for iteration k
    float4 ra[4], rb[4];
#pragma unroll
    for (int k = 1; k <= 3; ++k) {
        ra[k] = ((const float4*)(xrow + k * 64))[0];
        rb[k] = ((const float4*)(xrow + k * 64))[1];
    }

    f32x4 acc[2][3];
#pragma unroll
    for (int mt = 0; mt < 2; ++mt)
#pragma unroll
        for (int nt = 0; nt < 3; ++nt) acc[mt][nt] = (f32x4){0.f, 0.f, 0.f, 0.f};

    __syncthreads();

#pragma unroll
    for (int kt = 0; kt < 16; ++kt) {
        const int cur = kt & 1;
        if (kt + 4 <= 15) {
            ra[kt & 3] = ((const float4*)(xrow + (kt + 4) * 64))[0];
            rb[kt & 3] = ((const float4*)(xrow + (kt + 4) * 64))[1];
        }
#pragma unroll
        for (int h = 0; h < 2; ++h) {
            const bf16x8 af0 = *(const bf16x8*)&xs[cur][c][h * 32 + quad * 8];
            const bf16x8 af1 = *(const bf16x8*)&xs[cur][16 + c][h * 32 + quad * 8];
#pragma unroll
            for (int nt = 0; nt < 3; ++nt) {
                const int ntg = w * 3 + nt;
                const bf16x8 bf = *(const bf16x8*)&Wtf[((((size_t)ntg * 16 + kt) * 2 + h) * 64 + l) * 8];
                acc[0][nt] = __builtin_amdgcn_mfma_f32_16x16x32_bf16(af0, bf, acc[0][nt], 0, 0, 0);
                acc[1][nt] = __builtin_amdgcn_mfma_f32_16x16x32_bf16(af1, bf, acc[1][nt], 0, 0, 0);
            }
        }
        if (kt < 15)
            *(bf16x8*)&xs[1 - cur][r0][kc * 8] = pack8(ra[(kt + 1) & 3], rb[(kt + 1) & 3]);
        __syncthreads();
    }

#pragma unroll
    for (int nt = 0; nt < 3; ++nt) {
        const int col = w * 48 + nt * 16 + c;
        const int mat = col >> 6, cm = col & 63;
        const float bias = (mat == 0 ? bq : (mat == 1 ? bk : bv))[cm];
#pragma unroll
        for (int mt = 0; mt < 2; ++mt) {
            if (mat == 2) {
                const int row = ibase + mt * 16 + quad * 4;
                const int b = row >> 11, i = row & (Nn - 1);
                float4 o;
                o.x = acc[mt][nt][0] + bias;
                o.y = acc[mt][nt][1] + bias;
                o.z = acc[mt][nt][2] + bias;
                o.w = acc[mt][nt][3] + bias;
                *(float4*)&Vtf32[((size_t)b * DHn + cm) * Nn + i] = o;
            } else {
                const float s = (mat == 1) ? 0.125f : 1.0f;
                short* Out = (mat == 0) ? Qb : Kb;
#pragma unroll
                for (int r = 0; r < 4; ++r)
                    Out[(size_t)(ibase + mt * 16 + quad * 4 + r) * DHn + cm] =
                        f2bf((acc[mt][nt][r] + bias) * s);
            }
        }
    }
}

// ---------------------------------------------------------------------------
// K2: l_part[s][b][j] = sum_{i in split s} exp(Q_i . K'_j).
// b = bid&7 so each XCD's L2 holds only its batch's Q/K.
// BARRIER-FREE main loop: Q A-frags read directly from global (L2-resident,
// no LDS round-trip), K frags register-resident.  LDS = 4 KB reduction only.
// ---------------------------------------------------------------------------
__global__ __launch_bounds__(256) void colsum_kernel(
    const short* __restrict__ Qb, const short* __restrict__ Kb,
    float* __restrict__ lpart)
{
    __shared__ float red[16][64];

    const int t = threadIdx.x;
    const int w = t >> 6, l = t & 63;
    const int c = l & 15, quad = l >> 4;
    const int bid = blockIdx.x;
    const int b = bid & 7, jt = (bid >> 3) & 31, s = bid >> 8;
    const int jbase = jt * 64;

    bf16x8 kb[4][2];
#pragma unroll
    for (int nt = 0; nt < 4; ++nt)
#pragma unroll
        for (int kk = 0; kk < 2; ++kk)
            kb[nt][kk] = *(const bf16x8*)&Kb[((size_t)b * Nn + jbase + nt * 16 + c) * DHn
                                             + kk * 32 + quad * 8];

    // wave w owns contiguous 128 i: s*512 + w*128
    const short* qb0 = &Qb[((size_t)b * Nn + s * 512 + w * 128 + c) * DHn];

    float lsum[4] = {0.f, 0.f, 0.f, 0.f};

#pragma unroll
    for (int it2 = 0; it2 < 4; ++it2) {
#pragma unroll
        for (int cc2 = 0; cc2 < 2; ++cc2) {
            const short* qr = qb0 + (size_t)(it2 * 32 + cc2 * 16) * DHn;
            const bf16x8 aq0 = *(const bf16x8*)(qr + quad * 8);
            const bf16x8 aq1 = *(const bf16x8*)(qr + 32 + quad * 8);
#pragma unroll
            for (int nt = 0; nt < 4; ++nt) {
                f32x4 sv = (f32x4){0.f, 0.f, 0.f, 0.f};
                sv = __builtin_amdgcn_mfma_f32_16x16x32_bf16(aq0, kb[nt][0], sv, 0, 0, 0);
                sv = __builtin_amdgcn_mfma_f32_16x16x32_bf16(aq1, kb[nt][1], sv, 0, 0, 0);
                lsum[nt] += __expf(sv[0]) + __expf(sv[1]) + __expf(sv[2]) + __expf(sv[3]);
            }
        }
    }

#pragma unroll
    for (int nt = 0; nt < 4; ++nt) red[w * 4 + quad][nt * 16 + c] = lsum[nt];
    __syncthreads();
    if (t < 64) {
        float sum = 0.f;
#pragma unroll
        for (int r = 0; r < 16; ++r) sum += red[r][t];
        lpart[((size_t)s * Bn + b) * Nn + jbase + t] = sum;   // plain store
    }
}

// ---------------------------------------------------------------------------
// K2b: Vt[b][d][j] = bf16( Vtf32[b][d][j] / l_j ).
// ---------------------------------------------------------------------------
__global__ __launch_bounds__(256) void vscale_kernel(
    const float* __restrict__ lpart, const float* __restrict__ Vtf32,
    short* __restrict__ Vt)
{
    const int idx = blockIdx.x * 256 + threadIdx.x;   // 131072 = 8*64*256
    const int b = idx >> 14;
    const int d = (idx >> 8) & 63;
    const int j0 = (idx & 255) * 8;
    const size_t off = ((size_t)b * DHn + d) * Nn + j0;
    const size_t lj = (size_t)b * Nn + j0;

    const float* l0 = &lpart[lj];
    float4 sa = ((const float4*)l0)[0];
    float4 sb = ((const float4*)l0)[1];
#pragma unroll
    for (int s = 1; s < 4; ++s) {
        const float4 a = ((const float4*)(l0 + (size_t)s * Bn * Nn))[0];
        const float4 c = ((const float4*)(l0 + (size_t)s * Bn * Nn))[1];
        sa.x += a.x; sa.y += a.y; sa.z += a.z; sa.w += a.w;
        sb.x += c.x; sb.y += c.y; sb.z += c.z; sb.w += c.w;
    }
    float4 va = ((const float4*)&Vtf32[off])[0];
    float4 vb = ((const float4*)&Vtf32[off])[1];
    va.x /= sa.x; va.y /= sa.y; va.z /= sa.z; va.w /= sa.w;
    vb.x /= sb.x; vb.y /= sb.y; vb.z /= sb.z; vb.w /= sb.w;
    *(bf16x8*)&Vt[off] = pack8(va, vb);
}

// ---------------------------------------------------------------------------
// K3: outp[s][i,:] = sum_{j in s} exp(Q_i.K'_j) V'[j,:].
// Grid = (b 8, it 32, s 4) = 1024, b = bid&7 (XCD-local Q/K/V).
// BARRIER-FREE: no K/V LDS staging (64 KB slices are L2-resident, reused 32x
// across blocks on the same XCD); K/V B-frags loaded straight from global.
// Wave = 16 i-rows; Pt (wave-private, dbuf by tile parity) is the only LDS.
// SWAPPED QK^T: mfma(K,Q) -> S^T frag so the P transpose is b64 writes.
// ---------------------------------------------------------------------------
__global__ __launch_bounds__(256) void attnout_kernel(
    const short* __restrict__ Qb, const short* __restrict__ Kb,
    const short* __restrict__ Vt, float* __restrict__ outp)
{
    __shared__ __attribute__((aligned(16))) short Pt[4][2][16][PADP];  // [w][parity][i][j]

    const int t = threadIdx.x;
    const int w = t >> 6, lane = t & 63;
    const int c = lane & 15, quad = lane >> 4;
    const int bid = blockIdx.x;
    const int b = bid & 7, it = (bid >> 3) & 31, s = bid >> 8;
    const int ibase = it * 64;

    // Q B-frags (swapped mfma uses Q as B operand): wave's 16 i-rows
    const size_t qrow = (size_t)b * Nn + ibase + w * 16 + c;
    const bf16x8 aq0 = *(const bf16x8*)&Qb[qrow * DHn + quad * 8];
    const bf16x8 aq1 = *(const bf16x8*)&Qb[qrow * DHn + 32 + quad * 8];

    const short* K0 = &Kb[((size_t)b * Nn + s * 512) * DHn];
    const short* V0 = &Vt[(size_t)b * DHn * Nn + s * 512];

    f32x4 acc[4];
#pragma unroll
    for (int dn = 0; dn < 4; ++dn) acc[dn] = (f32x4){0.f, 0.f, 0.f, 0.f};

#pragma unroll 2
    for (int jt2 = 0; jt2 < 8; ++jt2) {
        const int cur = jt2 & 1;
        // S^T: lane c holds S[i=c][j = nt*16 + quad*4 + r]; write b64 to Pt
#pragma unroll
        for (int nt = 0; nt < 4; ++nt) {
            const short* kr = K0 + (size_t)(jt2 * 64 + nt * 16 + c) * DHn;
            const bf16x8 kb0 = *(const bf16x8*)(kr + quad * 8);
            const bf16x8 kb1 = *(const bf16x8*)(kr + 32 + quad * 8);
            f32x4 sv = (f32x4){0.f, 0.f, 0.f, 0.f};
            sv = __builtin_amdgcn_mfma_f32_16x16x32_bf16(kb0, aq0, sv, 0, 0, 0);
            sv = __builtin_amdgcn_mfma_f32_16x16x32_bf16(kb1, aq1, sv, 0, 0, 0);
            ushort4 o;
            o.x = (unsigned short)f2bf(__expf(sv[0]));
            o.y = (unsigned short)f2bf(__expf(sv[1]));
            o.z = (unsigned short)f2bf(__expf(sv[2]));
            o.w = (unsigned short)f2bf(__expf(sv[3]));
            *(ushort4*)&Pt[w][cur][c][nt * 16 + quad * 4] = o;
        }
        // A-frags from Pt (wave-private, same-wave DS in-order -> no barrier)
        const bf16x8 ap0 = *(const bf16x8*)&Pt[w][cur][c][quad * 8];
        const bf16x8 ap1 = *(const bf16x8*)&Pt[w][cur][c][32 + quad * 8];
#pragma unroll
        for (int dn = 0; dn < 4; ++dn) {
            const short* vr = V0 + (size_t)(dn * 16 + c) * Nn + jt2 * 64;
            const bf16x8 vb0 = *(const bf16x8*)(vr + quad * 8);
            const bf16x8 vb1 = *(const bf16x8*)(vr + 32 + quad * 8);
            acc[dn] = __builtin_amdgcn_mfma_f32_16x16x32_bf16(ap0, vb0, acc[dn], 0, 0, 0);
            acc[dn] = __builtin_amdgcn_mfma_f32_16x16x32_bf16(ap1, vb1, acc[dn], 0, 0, 0);
        }
    }

    float* op = outp + (size_t)s * (Bn * Nn * DHn) + ((size_t)b * Nn + ibase) * DHn;
#pragma unroll
    for (int dn = 0; dn < 4; ++dn)
#pragma unroll
        for (int r = 0; r < 4; ++r)
            op[(w * 16 + quad * 4 + r) * DHn + dn * 16 + c] = acc[dn][r];
}

// ---------------------------------------------------------------------------
// Reduce the 4 partial buffers into out.
// ---------------------------------------------------------------------------
__global__ __launch_bounds__(256) void outreduce_kernel(
    const float* __restrict__ outp, float* __restrict__ out)
{
    const int id = blockIdx.x * 256 + threadIdx.x;   // 262144 float4
    const float4* p = (const float4*)outp;
    float4 r = p[id];
#pragma unroll
    for (int k = 1; k < 4; ++k) {
        const float4 a = p[id + (size_t)k * 262144];
        r.x += a.x; r.y += a.y; r.z += a.z; r.w += a.w;
    }
    ((float4*)out)[id] = r;
}

// ---------------------------------------------------------------------------
extern "C" void kernel_launch(void* const* d_in, const int* in_sizes, int n_in,
                              void* d_out, int out_size, void* d_ws, size_t ws_size,
                              hipStream_t stream)
{
    const float* x  = (const float*)d_in[0];
    const float* Wq = (const float*)d_in[1];
    const float* bq = (const float*)d_in[2];
    const float* Wk = (const float*)d_in[3];
    const float* bk = (const float*)d_in[4];
    const float* Wv = (const float*)d_in[5];
    const float* bv = (const float*)d_in[6];
    float* out = (float*)d_out;

    char* ws = (char*)d_ws;
    short* Qb    = (short*)(ws);                                   // 2 MB
    short* Kb    = (short*)(ws + (size_t)(1 << 21));               // 2 MB
    short* Vt    = (short*)(ws + (size_t)(2 << 21));               // 2 MB [b][d][j] bf16 (scaled)
    short* Wtf   = (short*)(ws + (size_t)(3 << 21));               // 384 KB (frag-major)
    float* lpart = (float*)(ws + (size_t)(3 << 21) + (1 << 19));   // 256 KB (4 splits)
    float* Vtf32 = (float*)(ws + (size_t)(7 << 20));               // 4 MB [b][d][j] f32
    float* outp  = (float*)(ws + (size_t)(11 << 20));              // 16 MB (4 partials)

    wt_kernel<<<dim3(192), dim3(128), 0, stream>>>(Wq, Wk, Wv, Wtf);
    qkv_kernel<<<dim3(512), dim3(256), 0, stream>>>(x, Wtf, bq, bk, bv, Qb, Kb, Vtf32);
    colsum_kernel<<<dim3(1024), dim3(256), 0, stream>>>(Qb, Kb, lpart);
    vscale_kernel<<<dim3(512), dim3(256), 0, stream>>>(lpart, Vtf32, Vt);
    attnout_kernel<<<dim3(1024), dim3(256), 0, stream>>>(Qb, Kb, Vt, outp);
    outreduce_kernel<<<dim3(1024), dim3(256), 0, stream>>>(outp, out);
}

// Round 4
// 149.933 us; speedup vs baseline: 1.9656x; 1.3183x over previous
//
#include <hip/hip_runtime.h>
#include <math.h>

// Problem constants (HeadAttention_738734374917)
#define Bn  8
#define Nn  2048
#define Dn  1024
#define DHn 64
#define PAD  72  // LDS row pitch (shorts): 144B, keeps b128 16B-aligned; frag-read granules uniform

typedef __attribute__((ext_vector_type(8))) short bf16x8;  // 8 bf16 = 4 VGPRs
typedef __attribute__((ext_vector_type(4))) float f32x4;

static __device__ inline short f2bf(float f) {
    unsigned u = __builtin_bit_cast(unsigned, f);
    u += 0x7FFFu + ((u >> 16) & 1u);     // round-to-nearest-even
    return (short)(u >> 16);
}
static __device__ inline bf16x8 pack8(float4 a, float4 b) {
    bf16x8 v;
    v[0] = f2bf(a.x); v[1] = f2bf(a.y); v[2] = f2bf(a.z); v[3] = f2bf(a.w);
    v[4] = f2bf(b.x); v[5] = f2bf(b.y); v[6] = f2bf(b.z); v[7] = f2bf(b.w);
    return v;
}

// ---------------------------------------------------------------------------
// Wt in B-FRAG-MAJOR order: Wtf[ntg 0..11][kt 0..15][half 0..1][lane 0..63][e 0..7]
// Coalesced 32B loads -> LDS transpose -> b128 frag store.
// ---------------------------------------------------------------------------
__global__ __launch_bounds__(128) void wt_kernel(
    const float* __restrict__ Wq, const float* __restrict__ Wk,
    const float* __restrict__ Wv, short* __restrict__ Wtf)
{
    __shared__ float wsm[64][20];   // [k][n], pad 20 keeps float4 stores 16B-aligned
    const int nt = blockIdx.x / 16, kt = blockIdx.x % 16;
    const int t = threadIdx.x;

    const int mat = nt >> 2;
    const float* Wm = (mat == 0) ? Wq : (mat == 1 ? Wk : Wv);
    {
        const int k = t >> 1, n8 = (t & 1) * 8;
        const float* src = &Wm[(size_t)(kt * 64 + k) * DHn + (nt & 3) * 16 + n8];
        const float4 f0 = ((const float4*)src)[0];
        const float4 f1 = ((const float4*)src)[1];
        *(float4*)&wsm[k][n8]     = f0;
        *(float4*)&wsm[k][n8 + 4] = f1;
    }
    __syncthreads();
    const int half = t >> 6, l = t & 63;
    const int c = l & 15, quad = l >> 4;
    bf16x8 o;
#pragma unroll
    for (int e = 0; e < 8; ++e) o[e] = f2bf(wsm[half * 32 + quad * 8 + e][c]);
    *(bf16x8*)&Wtf[((((size_t)nt * 16 + kt) * 2 + half) * 64 + l) * 8] = o;
}

// ---------------------------------------------------------------------------
// K1: QKV projection: M=32, grid 512, dbuf xs, one barrier/kt, frag-major Wtf.
// 4-deep register-ring x prefetch (static indices via full unroll).
// Outputs: Qb[i][d], Kb[j][d]*0.125 (bf16), Vtf32[b][d][j] (f32, pre-scale).
// ---------------------------------------------------------------------------
__global__ __launch_bounds__(256) void qkv_kernel(
    const float* __restrict__ x, const short* __restrict__ Wtf,
    const float* __restrict__ bq, const float* __restrict__ bk,
    const float* __restrict__ bv,
    short* __restrict__ Qb, short* __restrict__ Kb, float* __restrict__ Vtf32)
{
    __shared__ __attribute__((aligned(16))) short xs[2][32][PAD];

    const int t = threadIdx.x;
    const int w = t >> 6, l = t & 63;
    const int c = l & 15, quad = l >> 4;
    const int ibase = blockIdx.x * 32;
    const int r0 = t >> 3, kc = t & 7;

    const float* xrow = &x[(size_t)(ibase + r0) * Dn + kc * 8];

    {
        const float4 a = ((const float4*)xrow)[0];
        const float4 b = ((const float4*)xrow)[1];
        *(bf16x8*)&xs[0][r0][kc * 8] = pack8(a, b);
    }

    // register ring: slot (k & 3) holds x data for iteration k
    float4 ra[4], rb[4];
#pragma unroll
    for (int k = 1; k <= 3; ++k) {
        ra[k] = ((const float4*)(xrow + k * 64))[0];
        rb[k] = ((const float4*)(xrow + k * 64))[1];
    }

    f32x4 acc[2][3];
#pragma unroll
    for (int mt = 0; mt < 2; ++mt)
#pragma unroll
        for (int nt = 0; nt < 3; ++nt) acc[mt][nt] = (f32x4){0.f, 0.f, 0.f, 0.f};

    __syncthreads();

#pragma unroll
    for (int kt = 0; kt < 16; ++kt) {
        const int cur = kt & 1;
        if (kt + 4 <= 15) {
            ra[kt & 3] = ((const float4*)(xrow + (kt + 4) * 64))[0];
            rb[kt & 3] = ((const float4*)(xrow + (kt + 4) * 64))[1];
        }
#pragma unroll
        for (int h = 0; h < 2; ++h) {
            const bf16x8 af0 = *(const bf16x8*)&xs[cur][c][h * 32 + quad * 8];
            const bf16x8 af1 = *(const bf16x8*)&xs[cur][16 + c][h * 32 + quad * 8];
#pragma unroll
            for (int nt = 0; nt < 3; ++nt) {
                const int ntg = w * 3 + nt;
                const bf16x8 bf = *(const bf16x8*)&Wtf[((((size_t)ntg * 16 + kt) * 2 + h) * 64 + l) * 8];
                acc[0][nt] = __builtin_amdgcn_mfma_f32_16x16x32_bf16(af0, bf, acc[0][nt], 0, 0, 0);
                acc[1][nt] = __builtin_amdgcn_mfma_f32_16x16x32_bf16(af1, bf, acc[1][nt], 0, 0, 0);
            }
        }
        if (kt < 15)
            *(bf16x8*)&xs[1 - cur][r0][kc * 8] = pack8(ra[(kt + 1) & 3], rb[(kt + 1) & 3]);
        __syncthreads();
    }

#pragma unroll
    for (int nt = 0; nt < 3; ++nt) {
        const int col = w * 48 + nt * 16 + c;
        const int mat = col >> 6, cm = col & 63;
        const float bias = (mat == 0 ? bq : (mat == 1 ? bk : bv))[cm];
#pragma unroll
        for (int mt = 0; mt < 2; ++mt) {
            if (mat == 2) {
                const int row = ibase + mt * 16 + quad * 4;
                const int b = row >> 11, i = row & (Nn - 1);
                float4 o;
                o.x = acc[mt][nt][0] + bias;
                o.y = acc[mt][nt][1] + bias;
                o.z = acc[mt][nt][2] + bias;
                o.w = acc[mt][nt][3] + bias;
                *(float4*)&Vtf32[((size_t)b * DHn + cm) * Nn + i] = o;
            } else {
                const float s = (mat == 1) ? 0.125f : 1.0f;
                short* Out = (mat == 0) ? Qb : Kb;
#pragma unroll
                for (int r = 0; r < 4; ++r)
                    Out[(size_t)(ibase + mt * 16 + quad * 4 + r) * DHn + cm] =
                        f2bf((acc[mt][nt][r] + bias) * s);
            }
        }
    }
}

// ---------------------------------------------------------------------------
// K2: l_part[s][b][j] = sum_{i in split s} exp(Q_i . K'_j).
// b = bid&7 so each XCD's L2 holds only its batch's Q/K.
// r1 structure: K-frags register-resident; wave-private Q staging (dbuf,
// no barriers in the loop), TWO 16-row chunks per iter for exp-chain ILP.
// ---------------------------------------------------------------------------
__global__ __launch_bounds__(256) void colsum_kernel(
    const short* __restrict__ Qb, const short* __restrict__ Kb,
    float* __restrict__ lpart)
{
    __shared__ __attribute__((aligned(16))) short Qw[4][2][32][PAD];
    __shared__ float red[16][64];

    const int t = threadIdx.x;
    const int w = t >> 6, l = t & 63;
    const int c = l & 15, quad = l >> 4;
    const int bid = blockIdx.x;
    const int b = bid & 7, jt = (bid >> 3) & 31, s = bid >> 8;
    const int jbase = jt * 64;
    const int srow = l >> 1, scoff = (l & 1) * 32;   // staging: 32 rows, half-row/lane

    bf16x8 kb[4][2];
#pragma unroll
    for (int nt = 0; nt < 4; ++nt)
#pragma unroll
        for (int kk = 0; kk < 2; ++kk)
            kb[nt][kk] = *(const bf16x8*)&Kb[((size_t)b * Nn + jbase + nt * 16 + c) * DHn
                                             + kk * 32 + quad * 8];

    // wave w owns contiguous 128 i: s*512 + w*128, 4 iters of 32 rows
    const short* qbase = &Qb[((size_t)b * Nn + s * 512 + w * 128 + srow) * DHn + scoff];

    // stage it2=0 into buf 0 (wave-private, 4 b128/lane)
#pragma unroll
    for (int k = 0; k < 4; ++k)
        *(bf16x8*)&Qw[w][0][srow][scoff + k * 8] = *(const bf16x8*)(qbase + k * 8);

    float lsum[4] = {0.f, 0.f, 0.f, 0.f};

    for (int it2 = 0; it2 < 4; ++it2) {
        const int cur = it2 & 1;
        bf16x8 p[4];
        if (it2 < 3) {
            const short* pq = qbase + (size_t)(it2 + 1) * 32 * DHn;
#pragma unroll
            for (int k = 0; k < 4; ++k) p[k] = *(const bf16x8*)(pq + k * 8);
        }
        // two independent 16-row chunks
#pragma unroll
        for (int cc2 = 0; cc2 < 2; ++cc2) {
            const bf16x8 aq0 = *(const bf16x8*)&Qw[w][cur][cc2 * 16 + c][quad * 8];
            const bf16x8 aq1 = *(const bf16x8*)&Qw[w][cur][cc2 * 16 + c][32 + quad * 8];
#pragma unroll
            for (int nt = 0; nt < 4; ++nt) {
                f32x4 sv = (f32x4){0.f, 0.f, 0.f, 0.f};
                sv = __builtin_amdgcn_mfma_f32_16x16x32_bf16(aq0, kb[nt][0], sv, 0, 0, 0);
                sv = __builtin_amdgcn_mfma_f32_16x16x32_bf16(aq1, kb[nt][1], sv, 0, 0, 0);
                lsum[nt] += __expf(sv[0]) + __expf(sv[1]) + __expf(sv[2]) + __expf(sv[3]);
            }
        }
        if (it2 < 3) {
#pragma unroll
            for (int k = 0; k < 4; ++k)
                *(bf16x8*)&Qw[w][1 - cur][srow][scoff + k * 8] = p[k];
        }
        // no barrier: Qw[w] is wave-private, DS ops in-order per wave
    }

#pragma unroll
    for (int nt = 0; nt < 4; ++nt) red[w * 4 + quad][nt * 16 + c] = lsum[nt];
    __syncthreads();
    if (t < 64) {
        float sum = 0.f;
#pragma unroll
        for (int r = 0; r < 16; ++r) sum += red[r][t];
        lpart[((size_t)s * Bn + b) * Nn + jbase + t] = sum;   // plain store
    }
}

// ---------------------------------------------------------------------------
// K2b: Vt[b][d][j] = bf16( Vtf32[b][d][j] / l_j ).
// ---------------------------------------------------------------------------
__global__ __launch_bounds__(256) void vscale_kernel(
    const float* __restrict__ lpart, const float* __restrict__ Vtf32,
    short* __restrict__ Vt)
{
    const int idx = blockIdx.x * 256 + threadIdx.x;   // 131072 = 8*64*256
    const int b = idx >> 14;
    const int d = (idx >> 8) & 63;
    const int j0 = (idx & 255) * 8;
    const size_t off = ((size_t)b * DHn + d) * Nn + j0;
    const size_t lj = (size_t)b * Nn + j0;

    const float* l0 = &lpart[lj];
    float4 sa = ((const float4*)l0)[0];
    float4 sb = ((const float4*)l0)[1];
#pragma unroll
    for (int s = 1; s < 4; ++s) {
        const float4 a = ((const float4*)(l0 + (size_t)s * Bn * Nn))[0];
        const float4 c = ((const float4*)(l0 + (size_t)s * Bn * Nn))[1];
        sa.x += a.x; sa.y += a.y; sa.z += a.z; sa.w += a.w;
        sb.x += c.x; sb.y += c.y; sb.z += c.z; sb.w += c.w;
    }
    float4 va = ((const float4*)&Vtf32[off])[0];
    float4 vb = ((const float4*)&Vtf32[off])[1];
    va.x /= sa.x; va.y /= sa.y; va.z /= sa.z; va.w /= sa.w;
    vb.x /= sb.x; vb.y /= sb.y; vb.z /= sb.z; vb.w /= sb.w;
    *(bf16x8*)&Vt[off] = pack8(va, vb);
}

// ---------------------------------------------------------------------------
// K3: outp[s][i,:] = sum_{j in s} exp(Q_i.K'_j) V'[j,:].
// Grid = (b 8, it 32, s 4) = 1024, b = bid&7 (XCD-local Q/K/V).
// Staged dbuf K/V in LDS (latency-hidden bulk loads), 1 barrier/tile.
// ROW-PERMUTED K staging-read: loading A-frag rows in order
// pi(nt,c) = 8*(c>>2) + (c&1) + ((c&2)<<1) + 2*(nt&1) + 32*(nt>>1)
// makes each lane's S^T outputs exactly its own PV A-frag j-set
// (j = 8q+e / 32+8q+e) -> P stays in registers, NO P LDS round-trip.
// LDS 36.9KB -> 4 blocks/CU; __launch_bounds__(256,4) caps VGPR for 16 w/CU.
// ---------------------------------------------------------------------------
__global__ __launch_bounds__(256, 4) void attnout_kernel(
    const short* __restrict__ Qb, const short* __restrict__ Kb,
    const short* __restrict__ Vt, float* __restrict__ outp)
{
    __shared__ __attribute__((aligned(16))) short Ks[2][64][PAD];
    __shared__ __attribute__((aligned(16))) short Vs[2][64][PAD];

    const int t = threadIdx.x;
    const int w = t >> 6, lane = t & 63;
    const int c = lane & 15, quad = lane >> 4;
    const int bid = blockIdx.x;
    const int b = bid & 7, it = (bid >> 3) & 31, s = bid >> 8;
    const int ibase = it * 64;
    const int r0 = t >> 2, cc = (t & 3) * 16;

    // permuted A-frag row base for this lane: rows pi(nt,c) within the 64-tile
    const int prb = ((c >> 2) << 3) + (c & 1) + ((c & 2) << 1);

    // Q B-frags (swapped mfma uses Q as B operand): wave's 16 i-rows
    const size_t qrow = (size_t)b * Nn + ibase + w * 16 + c;
    const bf16x8 aq0 = *(const bf16x8*)&Qb[qrow * DHn + quad * 8];
    const bf16x8 aq1 = *(const bf16x8*)&Qb[qrow * DHn + 32 + quad * 8];

    const short* kbase = &Kb[((size_t)b * Nn + s * 512 + r0) * DHn + cc];
    const short* vbase = &Vt[((size_t)b * DHn + r0) * Nn + s * 512 + cc];

    // stage tile 0 into buf 0
    *(bf16x8*)&Ks[0][r0][cc]     = *(const bf16x8*)kbase;
    *(bf16x8*)&Ks[0][r0][cc + 8] = *(const bf16x8*)(kbase + 8);
    *(bf16x8*)&Vs[0][r0][cc]     = *(const bf16x8*)vbase;
    *(bf16x8*)&Vs[0][r0][cc + 8] = *(const bf16x8*)(vbase + 8);

    f32x4 acc[4];
#pragma unroll
    for (int dn = 0; dn < 4; ++dn) acc[dn] = (f32x4){0.f, 0.f, 0.f, 0.f};
    __syncthreads();

#pragma unroll 2
    for (int jt2 = 0; jt2 < 8; ++jt2) {
        const int cur = jt2 & 1;
        bf16x8 pk0, pk1, pv0, pv1;
        if (jt2 < 7) {
            const short* pk = kbase + (size_t)(jt2 + 1) * 64 * DHn;
            pk0 = *(const bf16x8*)pk; pk1 = *(const bf16x8*)(pk + 8);
            const short* pv = vbase + (jt2 + 1) * 64;
            pv0 = *(const bf16x8*)pv; pv1 = *(const bf16x8*)(pv + 8);
        }

        // S^T with permuted rows: sv[nt][r] = S[i=c][j = pi(nt, 4q+r)]
        f32x4 sv[4];
#pragma unroll
        for (int nt = 0; nt < 4; ++nt) {
            const int pr = prb + 2 * (nt & 1) + 32 * (nt >> 1);
            const bf16x8 kb0 = *(const bf16x8*)&Ks[cur][pr][quad * 8];
            const bf16x8 kb1 = *(const bf16x8*)&Ks[cur][pr][32 + quad * 8];
            f32x4 z = (f32x4){0.f, 0.f, 0.f, 0.f};
            z = __builtin_amdgcn_mfma_f32_16x16x32_bf16(kb0, aq0, z, 0, 0, 0);
            sv[nt] = __builtin_amdgcn_mfma_f32_16x16x32_bf16(kb1, aq1, z, 0, 0, 0);
        }

        // P frags entirely in-register:
        // ap_lo e=0..7 <-> j=8q+e ; ap_hi <-> j=32+8q+e
        bf16x8 ap_lo, ap_hi;
        ap_lo[0] = f2bf(__expf(sv[0][0])); ap_lo[1] = f2bf(__expf(sv[0][1]));
        ap_lo[2] = f2bf(__expf(sv[1][0])); ap_lo[3] = f2bf(__expf(sv[1][1]));
        ap_lo[4] = f2bf(__expf(sv[0][2])); ap_lo[5] = f2bf(__expf(sv[0][3]));
        ap_lo[6] = f2bf(__expf(sv[1][2])); ap_lo[7] = f2bf(__expf(sv[1][3]));
        ap_hi[0] = f2bf(__expf(sv[2][0])); ap_hi[1] = f2bf(__expf(sv[2][1]));
        ap_hi[2] = f2bf(__expf(sv[3][0])); ap_hi[3] = f2bf(__expf(sv[3][1]));
        ap_hi[4] = f2bf(__expf(sv[2][2])); ap_hi[5] = f2bf(__expf(sv[2][3]));
        ap_hi[6] = f2bf(__expf(sv[3][2])); ap_hi[7] = f2bf(__expf(sv[3][3]));

#pragma unroll
        for (int dn = 0; dn < 4; ++dn) {
            const bf16x8 vb0 = *(const bf16x8*)&Vs[cur][dn * 16 + c][quad * 8];
            const bf16x8 vb1 = *(const bf16x8*)&Vs[cur][dn * 16 + c][32 + quad * 8];
            acc[dn] = __builtin_amdgcn_mfma_f32_16x16x32_bf16(ap_lo, vb0, acc[dn], 0, 0, 0);
            acc[dn] = __builtin_amdgcn_mfma_f32_16x16x32_bf16(ap_hi, vb1, acc[dn], 0, 0, 0);
        }

        if (jt2 < 7) {
            *(bf16x8*)&Ks[1 - cur][r0][cc]     = pk0;
            *(bf16x8*)&Ks[1 - cur][r0][cc + 8] = pk1;
            *(bf16x8*)&Vs[1 - cur][r0][cc]     = pv0;
            *(bf16x8*)&Vs[1 - cur][r0][cc + 8] = pv1;
        }
        __syncthreads();
    }

    float* op = outp + (size_t)s * (Bn * Nn * DHn) + ((size_t)b * Nn + ibase) * DHn;
#pragma unroll
    for (int dn = 0; dn < 4; ++dn)
#pragma unroll
        for (int r = 0; r < 4; ++r)
            op[(w * 16 + quad * 4 + r) * DHn + dn * 16 + c] = acc[dn][r];
}

// ---------------------------------------------------------------------------
// Reduce the 4 partial buffers into out.
// ---------------------------------------------------------------------------
__global__ __launch_bounds__(256) void outreduce_kernel(
    const float* __restrict__ outp, float* __restrict__ out)
{
    const int id = blockIdx.x * 256 + threadIdx.x;   // 262144 float4
    const float4* p = (const float4*)outp;
    float4 r = p[id];
#pragma unroll
    for (int k = 1; k < 4; ++k) {
        const float4 a = p[id + (size_t)k * 262144];
        r.x += a.x; r.y += a.y; r.z += a.z; r.w += a.w;
    }
    ((float4*)out)[id] = r;
}

// ---------------------------------------------------------------------------
extern "C" void kernel_launch(void* const* d_in, const int* in_sizes, int n_in,
                              void* d_out, int out_size, void* d_ws, size_t ws_size,
                              hipStream_t stream)
{
    const float* x  = (const float*)d_in[0];
    const float* Wq = (const float*)d_in[1];
    const float* bq = (const float*)d_in[2];
    const float* Wk = (const float*)d_in[3];
    const float* bk = (const float*)d_in[4];
    const float* Wv = (const float*)d_in[5];
    const float* bv = (const float*)d_in[6];
    float* out = (float*)d_out;

    char* ws = (char*)d_ws;
    short* Qb    = (short*)(ws);                                   // 2 MB
    short* Kb    = (short*)(ws + (size_t)(1 << 21));               // 2 MB
    short* Vt    = (short*)(ws + (size_t)(2 << 21));               // 2 MB [b][d][j] bf16 (scaled)
    short* Wtf   = (short*)(ws + (size_t)(3 << 21));               // 384 KB (frag-major)
    float* lpart = (float*)(ws + (size_t)(3 << 21) + (1 << 19));   // 256 KB (4 splits)
    float* Vtf32 = (float*)(ws + (size_t)(7 << 20));               // 4 MB [b][d][j] f32
    float* outp  = (float*)(ws + (size_t)(11 << 20));              // 16 MB (4 partials)

    wt_kernel<<<dim3(192), dim3(128), 0, stream>>>(Wq, Wk, Wv, Wtf);
    qkv_kernel<<<dim3(512), dim3(256), 0, stream>>>(x, Wtf, bq, bk, bv, Qb, Kb, Vtf32);
    colsum_kernel<<<dim3(1024), dim3(256), 0, stream>>>(Qb, Kb, lpart);
    vscale_kernel<<<dim3(512), dim3(256), 0, stream>>>(lpart, Vtf32, Vt);
    attnout_kernel<<<dim3(1024), dim3(256), 0, stream>>>(Qb, Kb, Vt, outp);
    outreduce_kernel<<<dim3(1024), dim3(256), 0, stream>>>(outp, out);
}

// Round 6
// 149.699 us; speedup vs baseline: 1.9687x; 1.0016x over previous
//
#include <hip/hip_runtime.h>
#include <math.h>

// Problem constants (HeadAttention_738734374917)
#define Bn  8
#define Nn  2048
#define Dn  1024
#define DHn 64
#define PAD  72  // LDS row pitch (shorts): 144B, keeps b128 16B-aligned

typedef __attribute__((ext_vector_type(8))) short bf16x8;  // 8 bf16 = 4 VGPRs
typedef __attribute__((ext_vector_type(4))) float f32x4;

static __device__ inline short f2bf(float f) {
    unsigned u = __builtin_bit_cast(unsigned, f);
    u += 0x7FFFu + ((u >> 16) & 1u);     // round-to-nearest-even
    return (short)(u >> 16);
}
static __device__ inline bf16x8 pack8(float4 a, float4 b) {
    bf16x8 v;
    v[0] = f2bf(a.x); v[1] = f2bf(a.y); v[2] = f2bf(a.z); v[3] = f2bf(a.w);
    v[4] = f2bf(b.x); v[5] = f2bf(b.y); v[6] = f2bf(b.z); v[7] = f2bf(b.w);
    return v;
}

// ---------------------------------------------------------------------------
// Wt in B-FRAG-MAJOR order: Wtf[ntg 0..11][kt 0..15][half 0..1][lane 0..63][e 0..7]
// Coalesced 32B loads -> LDS transpose -> b128 frag store.
// ---------------------------------------------------------------------------
__global__ __launch_bounds__(128) void wt_kernel(
    const float* __restrict__ Wq, const float* __restrict__ Wk,
    const float* __restrict__ Wv, short* __restrict__ Wtf)
{
    __shared__ float wsm[64][20];   // [k][n], pad 20 keeps float4 stores 16B-aligned
    const int nt = blockIdx.x / 16, kt = blockIdx.x % 16;
    const int t = threadIdx.x;

    const int mat = nt >> 2;
    const float* Wm = (mat == 0) ? Wq : (mat == 1 ? Wk : Wv);
    {
        const int k = t >> 1, n8 = (t & 1) * 8;
        const float* src = &Wm[(size_t)(kt * 64 + k) * DHn + (nt & 3) * 16 + n8];
        const float4 f0 = ((const float4*)src)[0];
        const float4 f1 = ((const float4*)src)[1];
        *(float4*)&wsm[k][n8]     = f0;
        *(float4*)&wsm[k][n8 + 4] = f1;
    }
    __syncthreads();
    const int half = t >> 6, l = t & 63;
    const int c = l & 15, quad = l >> 4;
    bf16x8 o;
#pragma unroll
    for (int e = 0; e < 8; ++e) o[e] = f2bf(wsm[half * 32 + quad * 8 + e][c]);
    *(bf16x8*)&Wtf[((((size_t)nt * 16 + kt) * 2 + half) * 64 + l) * 8] = o;
}

// ---------------------------------------------------------------------------
// K1: QKV projection: M=32, grid 512, dbuf xs, one barrier/kt, frag-major Wtf.
// 4-deep register-ring x prefetch (static indices via full unroll).
// Outputs: Qb[i][d], Kb[j][d]*0.125, Vt[b][d][j] — all bf16.
// ---------------------------------------------------------------------------
__global__ __launch_bounds__(256) void qkv_kernel(
    const float* __restrict__ x, const short* __restrict__ Wtf,
    const float* __restrict__ bq, const float* __restrict__ bk,
    const float* __restrict__ bv,
    short* __restrict__ Qb, short* __restrict__ Kb, short* __restrict__ Vt)
{
    __shared__ __attribute__((aligned(16))) short xs[2][32][PAD];

    const int t = threadIdx.x;
    const int w = t >> 6, l = t & 63;
    const int c = l & 15, quad = l >> 4;
    const int ibase = blockIdx.x * 32;
    const int r0 = t >> 3, kc = t & 7;

    const float* xrow = &x[(size_t)(ibase + r0) * Dn + kc * 8];

    {
        const float4 a = ((const float4*)xrow)[0];
        const float4 b = ((const float4*)xrow)[1];
        *(bf16x8*)&xs[0][r0][kc * 8] = pack8(a, b);
    }

    // register ring: slot (k & 3) holds x data for iteration k
    float4 ra[4], rb[4];
#pragma unroll
    for (int k = 1; k <= 3; ++k) {
        ra[k] = ((const float4*)(xrow + k * 64))[0];
        rb[k] = ((const float4*)(xrow + k * 64))[1];
    }

    f32x4 acc[2][3];
#pragma unroll
    for (int mt = 0; mt < 2; ++mt)
#pragma unroll
        for (int nt = 0; nt < 3; ++nt) acc[mt][nt] = (f32x4){0.f, 0.f, 0.f, 0.f};

    __syncthreads();

#pragma unroll
    for (int kt = 0; kt < 16; ++kt) {
        const int cur = kt & 1;
        if (kt + 4 <= 15) {
            ra[kt & 3] = ((const float4*)(xrow + (kt + 4) * 64))[0];
            rb[kt & 3] = ((const float4*)(xrow + (kt + 4) * 64))[1];
        }
#pragma unroll
        for (int h = 0; h < 2; ++h) {
            const bf16x8 af0 = *(const bf16x8*)&xs[cur][c][h * 32 + quad * 8];
            const bf16x8 af1 = *(const bf16x8*)&xs[cur][16 + c][h * 32 + quad * 8];
#pragma unroll
            for (int nt = 0; nt < 3; ++nt) {
                const int ntg = w * 3 + nt;
                const bf16x8 bf = *(const bf16x8*)&Wtf[((((size_t)ntg * 16 + kt) * 2 + h) * 64 + l) * 8];
                acc[0][nt] = __builtin_amdgcn_mfma_f32_16x16x32_bf16(af0, bf, acc[0][nt], 0, 0, 0);
                acc[1][nt] = __builtin_amdgcn_mfma_f32_16x16x32_bf16(af1, bf, acc[1][nt], 0, 0, 0);
            }
        }
        if (kt < 15)
            *(bf16x8*)&xs[1 - cur][r0][kc * 8] = pack8(ra[(kt + 1) & 3], rb[(kt + 1) & 3]);
        __syncthreads();
    }

#pragma unroll
    for (int nt = 0; nt < 3; ++nt) {
        const int col = w * 48 + nt * 16 + c;
        const int mat = col >> 6, cm = col & 63;
        const float bias = (mat == 0 ? bq : (mat == 1 ? bk : bv))[cm];
#pragma unroll
        for (int mt = 0; mt < 2; ++mt) {
            if (mat == 2) {
                const int row = ibase + mt * 16 + quad * 4;
                const int b = row >> 11, i = row & (Nn - 1);
                ushort4 o;
                o.x = (unsigned short)f2bf(acc[mt][nt][0] + bias);
                o.y = (unsigned short)f2bf(acc[mt][nt][1] + bias);
                o.z = (unsigned short)f2bf(acc[mt][nt][2] + bias);
                o.w = (unsigned short)f2bf(acc[mt][nt][3] + bias);
                *(ushort4*)&Vt[((size_t)b * DHn + cm) * Nn + i] = o;
            } else {
                const float s = (mat == 1) ? 0.125f : 1.0f;
                short* Out = (mat == 0) ? Qb : Kb;
#pragma unroll
                for (int r = 0; r < 4; ++r)
                    Out[(size_t)(ibase + mt * 16 + quad * 4 + r) * DHn + cm] =
                        f2bf((acc[mt][nt][r] + bias) * s);
            }
        }
    }
}

// ---------------------------------------------------------------------------
// K2: l_part[s][b][j] = sum_{i in split s} exp(Q_i . K'_j).
// b = bid&7 so each XCD's L2 holds only its batch's Q/K.
// K-frags register-resident; wave-private Q staging (dbuf, no barriers in the
// loop), TWO 16-row chunks per iter for exp-chain ILP.
// ---------------------------------------------------------------------------
__global__ __launch_bounds__(256) void colsum_kernel(
    const short* __restrict__ Qb, const short* __restrict__ Kb,
    float* __restrict__ lpart)
{
    __shared__ __attribute__((aligned(16))) short Qw[4][2][32][PAD];
    __shared__ float red[16][64];

    const int t = threadIdx.x;
    const int w = t >> 6, l = t & 63;
    const int c = l & 15, quad = l >> 4;
    const int bid = blockIdx.x;
    const int b = bid & 7, jt = (bid >> 3) & 31, s = bid >> 8;
    const int jbase = jt * 64;
    const int srow = l >> 1, scoff = (l & 1) * 32;   // staging: 32 rows, half-row/lane

    bf16x8 kb[4][2];
#pragma unroll
    for (int nt = 0; nt < 4; ++nt)
#pragma unroll
        for (int kk = 0; kk < 2; ++kk)
            kb[nt][kk] = *(const bf16x8*)&Kb[((size_t)b * Nn + jbase + nt * 16 + c) * DHn
                                             + kk * 32 + quad * 8];

    // wave w owns contiguous 128 i: s*512 + w*128, 4 iters of 32 rows
    const short* qbase = &Qb[((size_t)b * Nn + s * 512 + w * 128 + srow) * DHn + scoff];

    // stage it2=0 into buf 0 (wave-private, 4 b128/lane)
#pragma unroll
    for (int k = 0; k < 4; ++k)
        *(bf16x8*)&Qw[w][0][srow][scoff + k * 8] = *(const bf16x8*)(qbase + k * 8);

    float lsum[4] = {0.f, 0.f, 0.f, 0.f};

    for (int it2 = 0; it2 < 4; ++it2) {
        const int cur = it2 & 1;
        bf16x8 p[4];
        if (it2 < 3) {
            const short* pq = qbase + (size_t)(it2 + 1) * 32 * DHn;
#pragma unroll
            for (int k = 0; k < 4; ++k) p[k] = *(const bf16x8*)(pq + k * 8);
        }
        // two independent 16-row chunks
#pragma unroll
        for (int cc2 = 0; cc2 < 2; ++cc2) {
            const bf16x8 aq0 = *(const bf16x8*)&Qw[w][cur][cc2 * 16 + c][quad * 8];
            const bf16x8 aq1 = *(const bf16x8*)&Qw[w][cur][cc2 * 16 + c][32 + quad * 8];
#pragma unroll
            for (int nt = 0; nt < 4; ++nt) {
                f32x4 sv = (f32x4){0.f, 0.f, 0.f, 0.f};
                sv = __builtin_amdgcn_mfma_f32_16x16x32_bf16(aq0, kb[nt][0], sv, 0, 0, 0);
                sv = __builtin_amdgcn_mfma_f32_16x16x32_bf16(aq1, kb[nt][1], sv, 0, 0, 0);
                lsum[nt] += __expf(sv[0]) + __expf(sv[1]) + __expf(sv[2]) + __expf(sv[3]);
            }
        }
        if (it2 < 3) {
#pragma unroll
            for (int k = 0; k < 4; ++k)
                *(bf16x8*)&Qw[w][1 - cur][srow][scoff + k * 8] = p[k];
        }
        // no barrier: Qw[w] is wave-private, DS ops in-order per wave
    }

#pragma unroll
    for (int nt = 0; nt < 4; ++nt) red[w * 4 + quad][nt * 16 + c] = lsum[nt];
    __syncthreads();
    if (t < 64) {
        float sum = 0.f;
#pragma unroll
        for (int r = 0; r < 16; ++r) sum += red[r][t];
        lpart[((size_t)s * Bn + b) * Nn + jbase + t] = sum;   // plain store
    }
}

// ---------------------------------------------------------------------------
// K3: out[i,:] = sum_j (exp(Q_i.K'_j)/l_j) V[j,:]  — FULL j per block.
// Grid = (b 8, it 64) = 512, b = bid&7 (XCD-local Q/K/V).  Block = 32 i-rows,
// 4 waves: wave w -> rows (w&1)*16, j-tile parity w>>1.  Each superstep
// stages 2 tiles (even+odd) dbuf'd, 1 barrier; waves consume their parity.
// Staging: 32 shorts (4 x b128) per thread for EACH of K and V = full 32 KB
// per superstep (r5's NaN was this at half-coverage).
// 1/l folded into in-register P via rls[2048] (one rcp per j, once per block).
// Pair partials merge through LDS (aliased on Ks), f32 out written directly.
// ---------------------------------------------------------------------------
__global__ __launch_bounds__(256, 2) void attnout_kernel(
    const short* __restrict__ Qb, const short* __restrict__ Kb,
    const short* __restrict__ Vt, const float* __restrict__ lpart,
    float* __restrict__ out)
{
    __shared__ __attribute__((aligned(16))) short Ks[2][2][64][PAD];  // [dbuf][parity][j][d]
    __shared__ __attribute__((aligned(16))) short Vs[2][2][64][PAD];  // [dbuf][parity][d][j]
    __shared__ float rls[2048];

    const int t = threadIdx.x;
    const int w = t >> 6, lane = t & 63;
    const int c = lane & 15, quad = lane >> 4;
    const int bid = blockIdx.x;
    const int b = bid & 7, it = bid >> 3;          // it 0..63
    const int ibase = it * 32;
    const int isub = (w & 1) * 16;                 // wave's 16 i-rows
    const int jp = w >> 1;                         // wave's tile parity

    // permuted A-frag row base: pi(nt,c) = prb + 2*(nt&1) + 32*(nt>>1)
    const int prb = ((c >> 2) << 3) + (c & 1) + ((c & 2) << 1);

    // rl[j] = 1 / sum_s lpart[s][b][j]  (coalesced, L2-resident)
#pragma unroll
    for (int k = 0; k < 8; ++k) {
        const int j = k * 256 + t;
        const size_t lj = (size_t)b * Nn + j;
        const float lv = lpart[lj] + lpart[(size_t)Bn * Nn + lj]
                       + lpart[2 * (size_t)Bn * Nn + lj] + lpart[3 * (size_t)Bn * Nn + lj];
        rls[j] = 1.0f / lv;
    }

    // Q B-frags (swapped mfma uses Q as B operand): wave's 16 i-rows
    const size_t qrow = (size_t)b * Nn + ibase + isub + c;
    const bf16x8 aq0 = *(const bf16x8*)&Qb[qrow * DHn + quad * 8];
    const bf16x8 aq1 = *(const bf16x8*)&Qb[qrow * DHn + 32 + quad * 8];

    // staging decomposition: 2 tiles = 32 KB / 256 threads = 128 B/thread
    const int r0k = t >> 1, ck = (t & 1) * 32;          // K: j-row 0..127, d-cols ck..ck+31
    const int pk_ = r0k >> 6, rk_ = r0k & 63;
    const int r0v = t >> 2, cv = (t & 3) * 32;          // V: d-row 0..63, j-cols cv..cv+31
    const int pv_ = cv >> 6, jv_ = cv & 63;
    const short* kbase = &Kb[((size_t)b * Nn + r0k) * DHn + ck];
    const short* vbase = &Vt[((size_t)b * DHn + r0v) * Nn + cv];

    // stage superstep 0 into buf 0 (4 b128 each for K and V)
#pragma unroll
    for (int q2 = 0; q2 < 4; ++q2) {
        *(bf16x8*)&Ks[0][pk_][rk_][ck + q2 * 8]  = *(const bf16x8*)(kbase + q2 * 8);
        *(bf16x8*)&Vs[0][pv_][r0v][jv_ + q2 * 8] = *(const bf16x8*)(vbase + q2 * 8);
    }

    f32x4 acc[4];
#pragma unroll
    for (int dn = 0; dn < 4; ++dn) acc[dn] = (f32x4){0.f, 0.f, 0.f, 0.f};
    __syncthreads();

    for (int ss = 0; ss < 16; ++ss) {
        const int cur = ss & 1;
        bf16x8 nk[4], nv[4];
        if (ss < 15) {
            const short* nkp = kbase + (size_t)(ss + 1) * 128 * DHn;
            const short* nvp = vbase + (ss + 1) * 128;
#pragma unroll
            for (int q2 = 0; q2 < 4; ++q2) {
                nk[q2] = *(const bf16x8*)(nkp + q2 * 8);
                nv[q2] = *(const bf16x8*)(nvp + q2 * 8);
            }
        }

        const int jt = 2 * ss + jp;                 // this wave's global tile
        // S^T with permuted rows: sv[nt][r] = S[i=c][j = pi(nt,4q+r)]
        f32x4 sv[4];
#pragma unroll
        for (int nt = 0; nt < 4; ++nt) {
            const int pr = prb + 2 * (nt & 1) + 32 * (nt >> 1);
            const bf16x8 kb0 = *(const bf16x8*)&Ks[cur][jp][pr][quad * 8];
            const bf16x8 kb1 = *(const bf16x8*)&Ks[cur][jp][pr][32 + quad * 8];
            f32x4 z = (f32x4){0.f, 0.f, 0.f, 0.f};
            z = __builtin_amdgcn_mfma_f32_16x16x32_bf16(kb0, aq0, z, 0, 0, 0);
            sv[nt] = __builtin_amdgcn_mfma_f32_16x16x32_bf16(kb1, aq1, z, 0, 0, 0);
        }

        // rl broadcast reads: lo j = jt*64 + 8q + e, hi +32
        const float* rlb = &rls[jt * 64 + quad * 8];
        const float4 rl0 = *(const float4*)rlb;
        const float4 rl1 = *(const float4*)(rlb + 4);
        const float4 rh0 = *(const float4*)(rlb + 32);
        const float4 rh1 = *(const float4*)(rlb + 36);

        // P frags in-register: ap_lo[e] <-> j=8q+e ; ap_hi <-> j=32+8q+e
        bf16x8 ap_lo, ap_hi;
        ap_lo[0] = f2bf(__expf(sv[0][0]) * rl0.x); ap_lo[1] = f2bf(__expf(sv[0][1]) * rl0.y);
        ap_lo[2] = f2bf(__expf(sv[1][0]) * rl0.z); ap_lo[3] = f2bf(__expf(sv[1][1]) * rl0.w);
        ap_lo[4] = f2bf(__expf(sv[0][2]) * rl1.x); ap_lo[5] = f2bf(__expf(sv[0][3]) * rl1.y);
        ap_lo[6] = f2bf(__expf(sv[1][2]) * rl1.z); ap_lo[7] = f2bf(__expf(sv[1][3]) * rl1.w);
        ap_hi[0] = f2bf(__expf(sv[2][0]) * rh0.x); ap_hi[1] = f2bf(__expf(sv[2][1]) * rh0.y);
        ap_hi[2] = f2bf(__expf(sv[3][0]) * rh0.z); ap_hi[3] = f2bf(__expf(sv[3][1]) * rh0.w);
        ap_hi[4] = f2bf(__expf(sv[2][2]) * rh1.x); ap_hi[5] = f2bf(__expf(sv[2][3]) * rh1.y);
        ap_hi[6] = f2bf(__expf(sv[3][2]) * rh1.z); ap_hi[7] = f2bf(__expf(sv[3][3]) * rh1.w);

#pragma unroll
        for (int dn = 0; dn < 4; ++dn) {
            const bf16x8 vb0 = *(const bf16x8*)&Vs[cur][jp][dn * 16 + c][quad * 8];
            const bf16x8 vb1 = *(const bf16x8*)&Vs[cur][jp][dn * 16 + c][32 + quad * 8];
            acc[dn] = __builtin_amdgcn_mfma_f32_16x16x32_bf16(ap_lo, vb0, acc[dn], 0, 0, 0);
            acc[dn] = __builtin_amdgcn_mfma_f32_16x16x32_bf16(ap_hi, vb1, acc[dn], 0, 0, 0);
        }

        if (ss < 15) {
#pragma unroll
            for (int q2 = 0; q2 < 4; ++q2) {
                *(bf16x8*)&Ks[1 - cur][pk_][rk_][ck + q2 * 8]  = nk[q2];
                *(bf16x8*)&Vs[1 - cur][pv_][r0v][jv_ + q2 * 8] = nv[q2];
            }
        }
        __syncthreads();
    }

    // pair reduction (waves jp=1 -> LDS aliased on Ks; jp=0 combines + writes)
    float* red = (float*)Ks;   // 32 rows x 65 f32 = 8320 B << sizeof(Ks)
    if (jp == 1) {
#pragma unroll
        for (int dn = 0; dn < 4; ++dn)
#pragma unroll
            for (int r = 0; r < 4; ++r)
                red[(isub + quad * 4 + r) * 65 + dn * 16 + c] = acc[dn][r];
    }
    __syncthreads();
    if (jp == 0) {
#pragma unroll
        for (int dn = 0; dn < 4; ++dn)
#pragma unroll
            for (int r = 0; r < 4; ++r) {
                const int row = isub + quad * 4 + r;
                out[((size_t)b * Nn + ibase + row) * DHn + dn * 16 + c] =
                    acc[dn][r] + red[row * 65 + dn * 16 + c];
            }
    }
}

// ---------------------------------------------------------------------------
extern "C" void kernel_launch(void* const* d_in, const int* in_sizes, int n_in,
                              void* d_out, int out_size, void* d_ws, size_t ws_size,
                              hipStream_t stream)
{
    const float* x  = (const float*)d_in[0];
    const float* Wq = (const float*)d_in[1];
    const float* bq = (const float*)d_in[2];
    const float* Wk = (const float*)d_in[3];
    const float* bk = (const float*)d_in[4];
    const float* Wv = (const float*)d_in[5];
    const float* bv = (const float*)d_in[6];
    float* out = (float*)d_out;

    char* ws = (char*)d_ws;
    short* Qb    = (short*)(ws);                                   // 2 MB
    short* Kb    = (short*)(ws + (size_t)(1 << 21));               // 2 MB
    short* Vt    = (short*)(ws + (size_t)(2 << 21));               // 2 MB [b][d][j] bf16
    short* Wtf   = (short*)(ws + (size_t)(3 << 21));               // 384 KB (frag-major)
    float* lpart = (float*)(ws + (size_t)(3 << 21) + (1 << 19));   // 256 KB (4 splits)

    wt_kernel<<<dim3(192), dim3(128), 0, stream>>>(Wq, Wk, Wv, Wtf);
    qkv_kernel<<<dim3(512), dim3(256), 0, stream>>>(x, Wtf, bq, bk, bv, Qb, Kb, Vt);
    colsum_kernel<<<dim3(1024), dim3(256), 0, stream>>>(Qb, Kb, lpart);
    attnout_kernel<<<dim3(512), dim3(256), 0, stream>>>(Qb, Kb, Vt, lpart, out);
}

// Round 7
// 149.336 us; speedup vs baseline: 1.9735x; 1.0024x over previous
//
#include <hip/hip_runtime.h>
#include <math.h>

// Problem constants (HeadAttention_738734374917)
#define Bn  8
#define Nn  2048
#define Dn  1024
#define DHn 64
#define PAD  72  // LDS row pitch (shorts): 144B, keeps b128 16B-aligned

typedef __attribute__((ext_vector_type(8))) short bf16x8;  // 8 bf16 = 4 VGPRs
typedef __attribute__((ext_vector_type(4))) float f32x4;

static __device__ inline short f2bf(float f) {
    unsigned u = __builtin_bit_cast(unsigned, f);
    u += 0x7FFFu + ((u >> 16) & 1u);     // round-to-nearest-even
    return (short)(u >> 16);
}
static __device__ inline bf16x8 pack8(float4 a, float4 b) {
    bf16x8 v;
    v[0] = f2bf(a.x); v[1] = f2bf(a.y); v[2] = f2bf(a.z); v[3] = f2bf(a.w);
    v[4] = f2bf(b.x); v[5] = f2bf(b.y); v[6] = f2bf(b.z); v[7] = f2bf(b.w);
    return v;
}

// ---------------------------------------------------------------------------
// Wt in B-FRAG-MAJOR order: Wtf[ntg 0..11][kt 0..15][half 0..1][lane 0..63][e 0..7]
// Coalesced 32B loads -> LDS transpose -> b128 frag store.
// ---------------------------------------------------------------------------
__global__ __launch_bounds__(128) void wt_kernel(
    const float* __restrict__ Wq, const float* __restrict__ Wk,
    const float* __restrict__ Wv, short* __restrict__ Wtf)
{
    __shared__ float wsm[64][20];   // [k][n], pad 20 keeps float4 stores 16B-aligned
    const int nt = blockIdx.x / 16, kt = blockIdx.x % 16;
    const int t = threadIdx.x;

    const int mat = nt >> 2;
    const float* Wm = (mat == 0) ? Wq : (mat == 1 ? Wk : Wv);
    {
        const int k = t >> 1, n8 = (t & 1) * 8;
        const float* src = &Wm[(size_t)(kt * 64 + k) * DHn + (nt & 3) * 16 + n8];
        const float4 f0 = ((const float4*)src)[0];
        const float4 f1 = ((const float4*)src)[1];
        *(float4*)&wsm[k][n8]     = f0;
        *(float4*)&wsm[k][n8 + 4] = f1;
    }
    __syncthreads();
    const int half = t >> 6, l = t & 63;
    const int c = l & 15, quad = l >> 4;
    bf16x8 o;
#pragma unroll
    for (int e = 0; e < 8; ++e) o[e] = f2bf(wsm[half * 32 + quad * 8 + e][c]);
    *(bf16x8*)&Wtf[((((size_t)nt * 16 + kt) * 2 + half) * 64 + l) * 8] = o;
}

// ---------------------------------------------------------------------------
// K1: QKV projection: M=32, grid 512, dbuf xs, one barrier/kt, frag-major Wtf.
// 4-deep register-ring x prefetch (static indices via full unroll).
// Outputs: Qb[i][d], Kb[j][d]*0.125, Vt[b][d][j] — all bf16.
// ---------------------------------------------------------------------------
__global__ __launch_bounds__(256) void qkv_kernel(
    const float* __restrict__ x, const short* __restrict__ Wtf,
    const float* __restrict__ bq, const float* __restrict__ bk,
    const float* __restrict__ bv,
    short* __restrict__ Qb, short* __restrict__ Kb, short* __restrict__ Vt)
{
    __shared__ __attribute__((aligned(16))) short xs[2][32][PAD];

    const int t = threadIdx.x;
    const int w = t >> 6, l = t & 63;
    const int c = l & 15, quad = l >> 4;
    const int ibase = blockIdx.x * 32;
    const int r0 = t >> 3, kc = t & 7;

    const float* xrow = &x[(size_t)(ibase + r0) * Dn + kc * 8];

    {
        const float4 a = ((const float4*)xrow)[0];
        const float4 b = ((const float4*)xrow)[1];
        *(bf16x8*)&xs[0][r0][kc * 8] = pack8(a, b);
    }

    // register ring: slot (k & 3) holds x data for iteration k
    float4 ra[4], rb[4];
#pragma unroll
    for (int k = 1; k <= 3; ++k) {
        ra[k] = ((const float4*)(xrow + k * 64))[0];
        rb[k] = ((const float4*)(xrow + k * 64))[1];
    }

    f32x4 acc[2][3];
#pragma unroll
    for (int mt = 0; mt < 2; ++mt)
#pragma unroll
        for (int nt = 0; nt < 3; ++nt) acc[mt][nt] = (f32x4){0.f, 0.f, 0.f, 0.f};

    __syncthreads();

#pragma unroll
    for (int kt = 0; kt < 16; ++kt) {
        const int cur = kt & 1;
        if (kt + 4 <= 15) {
            ra[kt & 3] = ((const float4*)(xrow + (kt + 4) * 64))[0];
            rb[kt & 3] = ((const float4*)(xrow + (kt + 4) * 64))[1];
        }
#pragma unroll
        for (int h = 0; h < 2; ++h) {
            const bf16x8 af0 = *(const bf16x8*)&xs[cur][c][h * 32 + quad * 8];
            const bf16x8 af1 = *(const bf16x8*)&xs[cur][16 + c][h * 32 + quad * 8];
#pragma unroll
            for (int nt = 0; nt < 3; ++nt) {
                const int ntg = w * 3 + nt;
                const bf16x8 bf = *(const bf16x8*)&Wtf[((((size_t)ntg * 16 + kt) * 2 + h) * 64 + l) * 8];
                acc[0][nt] = __builtin_amdgcn_mfma_f32_16x16x32_bf16(af0, bf, acc[0][nt], 0, 0, 0);
                acc[1][nt] = __builtin_amdgcn_mfma_f32_16x16x32_bf16(af1, bf, acc[1][nt], 0, 0, 0);
            }
        }
        if (kt < 15)
            *(bf16x8*)&xs[1 - cur][r0][kc * 8] = pack8(ra[(kt + 1) & 3], rb[(kt + 1) & 3]);
        __syncthreads();
    }

#pragma unroll
    for (int nt = 0; nt < 3; ++nt) {
        const int col = w * 48 + nt * 16 + c;
        const int mat = col >> 6, cm = col & 63;
        const float bias = (mat == 0 ? bq : (mat == 1 ? bk : bv))[cm];
#pragma unroll
        for (int mt = 0; mt < 2; ++mt) {
            if (mat == 2) {
                const int row = ibase + mt * 16 + quad * 4;
                const int b = row >> 11, i = row & (Nn - 1);
                ushort4 o;
                o.x = (unsigned short)f2bf(acc[mt][nt][0] + bias);
                o.y = (unsigned short)f2bf(acc[mt][nt][1] + bias);
                o.z = (unsigned short)f2bf(acc[mt][nt][2] + bias);
                o.w = (unsigned short)f2bf(acc[mt][nt][3] + bias);
                *(ushort4*)&Vt[((size_t)b * DHn + cm) * Nn + i] = o;
            } else {
                const float s = (mat == 1) ? 0.125f : 1.0f;
                short* Out = (mat == 0) ? Qb : Kb;
#pragma unroll
                for (int r = 0; r < 4; ++r)
                    Out[(size_t)(ibase + mt * 16 + quad * 4 + r) * DHn + cm] =
                        f2bf((acc[mt][nt][r] + bias) * s);
            }
        }
    }
}

// ---------------------------------------------------------------------------
// K2: l_part[s][b][j] = sum_{i in split s} exp(Q_i . K'_j).
// b = bid&7 so each XCD's L2 holds only its batch's Q/K.
// K-frags register-resident; wave-private Q staging (dbuf, no barriers in the
// loop), TWO 16-row chunks per iter for exp-chain ILP.
// ---------------------------------------------------------------------------
__global__ __launch_bounds__(256) void colsum_kernel(
    const short* __restrict__ Qb, const short* __restrict__ Kb,
    float* __restrict__ lpart)
{
    __shared__ __attribute__((aligned(16))) short Qw[4][2][32][PAD];
    __shared__ float red[16][64];

    const int t = threadIdx.x;
    const int w = t >> 6, l = t & 63;
    const int c = l & 15, quad = l >> 4;
    const int bid = blockIdx.x;
    const int b = bid & 7, jt = (bid >> 3) & 31, s = bid >> 8;
    const int jbase = jt * 64;
    const int srow = l >> 1, scoff = (l & 1) * 32;   // staging: 32 rows, half-row/lane

    bf16x8 kb[4][2];
#pragma unroll
    for (int nt = 0; nt < 4; ++nt)
#pragma unroll
        for (int kk = 0; kk < 2; ++kk)
            kb[nt][kk] = *(const bf16x8*)&Kb[((size_t)b * Nn + jbase + nt * 16 + c) * DHn
                                             + kk * 32 + quad * 8];

    // wave w owns contiguous 128 i: s*512 + w*128, 4 iters of 32 rows
    const short* qbase = &Qb[((size_t)b * Nn + s * 512 + w * 128 + srow) * DHn + scoff];

    // stage it2=0 into buf 0 (wave-private, 4 b128/lane)
#pragma unroll
    for (int k = 0; k < 4; ++k)
        *(bf16x8*)&Qw[w][0][srow][scoff + k * 8] = *(const bf16x8*)(qbase + k * 8);

    float lsum[4] = {0.f, 0.f, 0.f, 0.f};

    for (int it2 = 0; it2 < 4; ++it2) {
        const int cur = it2 & 1;
        bf16x8 p[4];
        if (it2 < 3) {
            const short* pq = qbase + (size_t)(it2 + 1) * 32 * DHn;
#pragma unroll
            for (int k = 0; k < 4; ++k) p[k] = *(const bf16x8*)(pq + k * 8);
        }
        // two independent 16-row chunks
#pragma unroll
        for (int cc2 = 0; cc2 < 2; ++cc2) {
            const bf16x8 aq0 = *(const bf16x8*)&Qw[w][cur][cc2 * 16 + c][quad * 8];
            const bf16x8 aq1 = *(const bf16x8*)&Qw[w][cur][cc2 * 16 + c][32 + quad * 8];
#pragma unroll
            for (int nt = 0; nt < 4; ++nt) {
                f32x4 sv = (f32x4){0.f, 0.f, 0.f, 0.f};
                sv = __builtin_amdgcn_mfma_f32_16x16x32_bf16(aq0, kb[nt][0], sv, 0, 0, 0);
                sv = __builtin_amdgcn_mfma_f32_16x16x32_bf16(aq1, kb[nt][1], sv, 0, 0, 0);
                lsum[nt] += __expf(sv[0]) + __expf(sv[1]) + __expf(sv[2]) + __expf(sv[3]);
            }
        }
        if (it2 < 3) {
#pragma unroll
            for (int k = 0; k < 4; ++k)
                *(bf16x8*)&Qw[w][1 - cur][srow][scoff + k * 8] = p[k];
        }
        // no barrier: Qw[w] is wave-private, DS ops in-order per wave
    }

#pragma unroll
    for (int nt = 0; nt < 4; ++nt) red[w * 4 + quad][nt * 16 + c] = lsum[nt];
    __syncthreads();
    if (t < 64) {
        float sum = 0.f;
#pragma unroll
        for (int r = 0; r < 16; ++r) sum += red[r][t];
        lpart[((size_t)s * Bn + b) * Nn + jbase + t] = sum;   // plain store
    }
}

// ---------------------------------------------------------------------------
// K3: outp[s][i,:] = sum_{j in s} (exp(Q_i.K'_j)/l_j) V[j,:].
// r4 structure (measured ~16us): grid (b 8, it 32, s 4) = 1024, 4 blocks/CU,
// staged dbuf K/V, 1 barrier/tile, ROW-PERMUTED in-register P (no P LDS).
// NEW: 1/l folded in-register via block-local rls[512] (2 KB LDS) — kills
// the vscale kernel and the Vtf32 round-trip.  LDS 38.9 KB -> 4 blocks/CU.
// ---------------------------------------------------------------------------
__global__ __launch_bounds__(256, 4) void attnout_kernel(
    const short* __restrict__ Qb, const short* __restrict__ Kb,
    const short* __restrict__ Vt, const float* __restrict__ lpart,
    float* __restrict__ outp)
{
    __shared__ __attribute__((aligned(16))) short Ks[2][64][PAD];
    __shared__ __attribute__((aligned(16))) short Vs[2][64][PAD];
    __shared__ float rls[512];

    const int t = threadIdx.x;
    const int w = t >> 6, lane = t & 63;
    const int c = lane & 15, quad = lane >> 4;
    const int bid = blockIdx.x;
    const int b = bid & 7, it = (bid >> 3) & 31, s = bid >> 8;
    const int ibase = it * 64;
    const int r0 = t >> 2, cc = (t & 3) * 16;

    // permuted A-frag row base: pi(nt,c) = prb + 2*(nt&1) + 32*(nt>>1)
    const int prb = ((c >> 2) << 3) + (c & 1) + ((c & 2) << 1);

    // rl[j] for this block's 512-j range (2 per thread, coalesced)
#pragma unroll
    for (int k = 0; k < 2; ++k) {
        const int jl = k * 256 + t;
        const size_t lj = (size_t)b * Nn + s * 512 + jl;
        const float lv = lpart[lj] + lpart[(size_t)Bn * Nn + lj]
                       + lpart[2 * (size_t)Bn * Nn + lj] + lpart[3 * (size_t)Bn * Nn + lj];
        rls[jl] = 1.0f / lv;
    }

    // Q B-frags (swapped mfma uses Q as B operand): wave's 16 i-rows
    const size_t qrow = (size_t)b * Nn + ibase + w * 16 + c;
    const bf16x8 aq0 = *(const bf16x8*)&Qb[qrow * DHn + quad * 8];
    const bf16x8 aq1 = *(const bf16x8*)&Qb[qrow * DHn + 32 + quad * 8];

    const short* kbase = &Kb[((size_t)b * Nn + s * 512 + r0) * DHn + cc];
    const short* vbase = &Vt[((size_t)b * DHn + r0) * Nn + s * 512 + cc];

    // stage tile 0 into buf 0
    *(bf16x8*)&Ks[0][r0][cc]     = *(const bf16x8*)kbase;
    *(bf16x8*)&Ks[0][r0][cc + 8] = *(const bf16x8*)(kbase + 8);
    *(bf16x8*)&Vs[0][r0][cc]     = *(const bf16x8*)vbase;
    *(bf16x8*)&Vs[0][r0][cc + 8] = *(const bf16x8*)(vbase + 8);

    f32x4 acc[4];
#pragma unroll
    for (int dn = 0; dn < 4; ++dn) acc[dn] = (f32x4){0.f, 0.f, 0.f, 0.f};
    __syncthreads();   // covers staging AND rls writes

#pragma unroll 2
    for (int jt2 = 0; jt2 < 8; ++jt2) {
        const int cur = jt2 & 1;
        bf16x8 pk0, pk1, pv0, pv1;
        if (jt2 < 7) {
            const short* pk = kbase + (size_t)(jt2 + 1) * 64 * DHn;
            pk0 = *(const bf16x8*)pk; pk1 = *(const bf16x8*)(pk + 8);
            const short* pv = vbase + (jt2 + 1) * 64;
            pv0 = *(const bf16x8*)pv; pv1 = *(const bf16x8*)(pv + 8);
        }

        // S^T with permuted rows: sv[nt][r] = S[i=c][j = pi(nt,4q+r)]
        f32x4 sv[4];
#pragma unroll
        for (int nt = 0; nt < 4; ++nt) {
            const int pr = prb + 2 * (nt & 1) + 32 * (nt >> 1);
            const bf16x8 kb0 = *(const bf16x8*)&Ks[cur][pr][quad * 8];
            const bf16x8 kb1 = *(const bf16x8*)&Ks[cur][pr][32 + quad * 8];
            f32x4 z = (f32x4){0.f, 0.f, 0.f, 0.f};
            z = __builtin_amdgcn_mfma_f32_16x16x32_bf16(kb0, aq0, z, 0, 0, 0);
            sv[nt] = __builtin_amdgcn_mfma_f32_16x16x32_bf16(kb1, aq1, z, 0, 0, 0);
        }

        // rl broadcast reads (16 lanes/quad share each float4 -> LDS broadcast)
        const float* rlb = &rls[jt2 * 64 + quad * 8];
        const float4 rl0 = *(const float4*)rlb;
        const float4 rl1 = *(const float4*)(rlb + 4);
        const float4 rh0 = *(const float4*)(rlb + 32);
        const float4 rh1 = *(const float4*)(rlb + 36);

        // P frags in-register: ap_lo[e] <-> j=8q+e ; ap_hi <-> j=32+8q+e
        bf16x8 ap_lo, ap_hi;
        ap_lo[0] = f2bf(__expf(sv[0][0]) * rl0.x); ap_lo[1] = f2bf(__expf(sv[0][1]) * rl0.y);
        ap_lo[2] = f2bf(__expf(sv[1][0]) * rl0.z); ap_lo[3] = f2bf(__expf(sv[1][1]) * rl0.w);
        ap_lo[4] = f2bf(__expf(sv[0][2]) * rl1.x); ap_lo[5] = f2bf(__expf(sv[0][3]) * rl1.y);
        ap_lo[6] = f2bf(__expf(sv[1][2]) * rl1.z); ap_lo[7] = f2bf(__expf(sv[1][3]) * rl1.w);
        ap_hi[0] = f2bf(__expf(sv[2][0]) * rh0.x); ap_hi[1] = f2bf(__expf(sv[2][1]) * rh0.y);
        ap_hi[2] = f2bf(__expf(sv[3][0]) * rh0.z); ap_hi[3] = f2bf(__expf(sv[3][1]) * rh0.w);
        ap_hi[4] = f2bf(__expf(sv[2][2]) * rh1.x); ap_hi[5] = f2bf(__expf(sv[2][3]) * rh1.y);
        ap_hi[6] = f2bf(__expf(sv[3][2]) * rh1.z); ap_hi[7] = f2bf(__expf(sv[3][3]) * rh1.w);

#pragma unroll
        for (int dn = 0; dn < 4; ++dn) {
            const bf16x8 vb0 = *(const bf16x8*)&Vs[cur][dn * 16 + c][quad * 8];
            const bf16x8 vb1 = *(const bf16x8*)&Vs[cur][dn * 16 + c][32 + quad * 8];
            acc[dn] = __builtin_amdgcn_mfma_f32_16x16x32_bf16(ap_lo, vb0, acc[dn], 0, 0, 0);
            acc[dn] = __builtin_amdgcn_mfma_f32_16x16x32_bf16(ap_hi, vb1, acc[dn], 0, 0, 0);
        }

        if (jt2 < 7) {
            *(bf16x8*)&Ks[1 - cur][r0][cc]     = pk0;
            *(bf16x8*)&Ks[1 - cur][r0][cc + 8] = pk1;
            *(bf16x8*)&Vs[1 - cur][r0][cc]     = pv0;
            *(bf16x8*)&Vs[1 - cur][r0][cc + 8] = pv1;
        }
        __syncthreads();
    }

    float* op = outp + (size_t)s * (Bn * Nn * DHn) + ((size_t)b * Nn + ibase) * DHn;
#pragma unroll
    for (int dn = 0; dn < 4; ++dn)
#pragma unroll
        for (int r = 0; r < 4; ++r)
            op[(w * 16 + quad * 4 + r) * DHn + dn * 16 + c] = acc[dn][r];
}

// ---------------------------------------------------------------------------
// Reduce the 4 partial buffers into out.
// ---------------------------------------------------------------------------
__global__ __launch_bounds__(256) void outreduce_kernel(
    const float* __restrict__ outp, float* __restrict__ out)
{
    const int id = blockIdx.x * 256 + threadIdx.x;   // 262144 float4
    const float4* p = (const float4*)outp;
    float4 r = p[id];
#pragma unroll
    for (int k = 1; k < 4; ++k) {
        const float4 a = p[id + (size_t)k * 262144];
        r.x += a.x; r.y += a.y; r.z += a.z; r.w += a.w;
    }
    ((float4*)out)[id] = r;
}

// ---------------------------------------------------------------------------
extern "C" void kernel_launch(void* const* d_in, const int* in_sizes, int n_in,
                              void* d_out, int out_size, void* d_ws, size_t ws_size,
                              hipStream_t stream)
{
    const float* x  = (const float*)d_in[0];
    const float* Wq = (const float*)d_in[1];
    const float* bq = (const float*)d_in[2];
    const float* Wk = (const float*)d_in[3];
    const float* bk = (const float*)d_in[4];
    const float* Wv = (const float*)d_in[5];
    const float* bv = (const float*)d_in[6];
    float* out = (float*)d_out;

    char* ws = (char*)d_ws;
    short* Qb    = (short*)(ws);                                   // 2 MB
    short* Kb    = (short*)(ws + (size_t)(1 << 21));               // 2 MB
    short* Vt    = (short*)(ws + (size_t)(2 << 21));               // 2 MB [b][d][j] bf16
    short* Wtf   = (short*)(ws + (size_t)(3 << 21));               // 384 KB (frag-major)
    float* lpart = (float*)(ws + (size_t)(3 << 21) + (1 << 19));   // 256 KB (4 splits)
    float* outp  = (float*)(ws + (size_t)(11 << 20));              // 16 MB (4 partials)

    wt_kernel<<<dim3(192), dim3(128), 0, stream>>>(Wq, Wk, Wv, Wtf);
    qkv_kernel<<<dim3(512), dim3(256), 0, stream>>>(x, Wtf, bq, bk, bv, Qb, Kb, Vt);
    colsum_kernel<<<dim3(1024), dim3(256), 0, stream>>>(Qb, Kb, lpart);
    attnout_kernel<<<dim3(1024), dim3(256), 0, stream>>>(Qb, Kb, Vt, lpart, outp);
    outreduce_kernel<<<dim3(1024), dim3(256), 0, stream>>>(outp, out);
}